// Round 3
// baseline (747.033 us; speedup 1.0000x reference)
//
#include <hip/hip_runtime.h>
#include <hip/hip_bf16.h>

// B=4, S=1024, D=2048, H=16, HD=128. SCALE = sqrt(128).
// d_out = [output fp32 (8388608)] ++ [attn fp32 (67108864)]
// ws layout (bf16): wq,wk,wv,wo [2048*2048 each] | Qh,Kh [B,H,S,HD] | Vt [B,H,HD,S] | ctx [B,S,D]
// attn region of d_out doubles as scratch for bf16 casts of q,k,v (dead before attn kernel writes).

typedef __attribute__((ext_vector_type(4))) float  f32x4;
typedef __attribute__((ext_vector_type(8))) short  bf16x8;   // 8 bf16 in 4 VGPRs
typedef __attribute__((ext_vector_type(4))) short  short4v;
typedef __attribute__((ext_vector_type(8))) short  short8v;

__device__ __forceinline__ short f2b(float f) {
  __hip_bfloat16 h = __float2bfloat16(f);
  return __builtin_bit_cast(short, h);
}

// ---------------- cast fp32 -> bf16, vectorized 8/thread ----------------
__global__ void cast_bf16(const float* __restrict__ in, __hip_bfloat16* __restrict__ out, size_t n) {
  size_t i0 = ((size_t)blockIdx.x * blockDim.x + threadIdx.x) * 8;
  size_t stride = (size_t)gridDim.x * blockDim.x * 8;
  for (size_t i = i0; i < n; i += stride) {
    float4 a = *(const float4*)(in + i);
    float4 b = *(const float4*)(in + i + 4);
    short8v o;
    o[0] = f2b(a.x); o[1] = f2b(a.y); o[2] = f2b(a.z); o[3] = f2b(a.w);
    o[4] = f2b(b.x); o[5] = f2b(b.y); o[6] = f2b(b.z); o[7] = f2b(b.w);
    *(short8v*)(out + i) = o;
  }
}

// ---------------- async global->LDS, 16B per lane ----------------
__device__ __forceinline__ void gload_lds16(const __hip_bfloat16* g, char* l) {
  __builtin_amdgcn_global_load_lds(
      (const __attribute__((address_space(1))) unsigned int*)g,
      (__attribute__((address_space(3))) unsigned int*)l, 16, 0, 0);
}

// ---------------- GEMM: C[m,n] = sum_k A[m,k]*Bt[n,k] + bias[n] ----------------
// m97 structure: 128x128 tile, 4 waves (each 64x64), BK=32, 16x16x32 bf16 MFMA.
// MODE 0: out bf16 to [B=4,H=16,S=1024,HD=128]   (Q,K heads)
// MODE 1: out bf16 to [B,H,HD,S] (V transposed)
// MODE 2: out fp32 row-major [M][N]              (final output)
template<int MODE>
__global__ __launch_bounds__(256, 2) void gemm_bt(
    const __hip_bfloat16* __restrict__ A,
    const __hip_bfloat16* __restrict__ Bt,
    const float* __restrict__ bias,
    void* __restrict__ outp,
    int M, int N, int K)
{
  __shared__ __align__(16) char As[128 * 64];  // 128 rows x 32 bf16
  __shared__ __align__(16) char Bs[128 * 64];
  const int tid  = threadIdx.x;
  const int lane = tid & 63, wid = tid >> 6;
  const int l16  = lane & 15, g = lane >> 4;
  const int m0 = blockIdx.y * 128, n0 = blockIdx.x * 128;
  const int wm = (wid >> 1) * 64, wn = (wid & 1) * 64;
  const size_t Kz = (size_t)K;

  f32x4 acc[4][4];
#pragma unroll
  for (int i = 0; i < 4; ++i)
#pragma unroll
    for (int j = 0; j < 4; ++j) acc[i][j] = f32x4{0.f, 0.f, 0.f, 0.f};

  const __hip_bfloat16* ga0 = A  + (size_t)(m0 + wid * 32 + (lane >> 2)) * Kz + (lane & 3) * 8;
  const __hip_bfloat16* gb0 = Bt + (size_t)(n0 + wid * 32 + (lane >> 2)) * Kz + (lane & 3) * 8;
  char* lA0 = As + wid * 2048;
  char* lB0 = Bs + wid * 2048;

  const int nk = K >> 5;
  for (int kt = 0; kt < nk; ++kt) {
    __syncthreads();
    gload_lds16(ga0,            lA0);
    gload_lds16(ga0 + 16 * Kz,  lA0 + 1024);
    gload_lds16(gb0,            lB0);
    gload_lds16(gb0 + 16 * Kz,  lB0 + 1024);
    ga0 += 32; gb0 += 32;
    asm volatile("s_waitcnt vmcnt(0)" ::: "memory");
    __syncthreads();
    bf16x8 a[4], b[4];
#pragma unroll
    for (int mf = 0; mf < 4; ++mf)
      a[mf] = *(const bf16x8*)(As + (wm + mf * 16 + l16) * 64 + g * 16);
#pragma unroll
    for (int nf = 0; nf < 4; ++nf)
      b[nf] = *(const bf16x8*)(Bs + (wn + nf * 16 + l16) * 64 + g * 16);
#pragma unroll
    for (int mf = 0; mf < 4; ++mf)
#pragma unroll
      for (int nf = 0; nf < 4; ++nf)
        acc[mf][nf] = __builtin_amdgcn_mfma_f32_16x16x32_bf16(a[mf], b[nf], acc[mf][nf], 0, 0, 0);
  }

  if (MODE == 2) {
    float* C = (float*)outp;
#pragma unroll
    for (int nf = 0; nf < 4; ++nf) {
      int col = n0 + wn + nf * 16 + l16;
      float bv = bias[col];
#pragma unroll
      for (int mf = 0; mf < 4; ++mf) {
        int row = m0 + wm + mf * 16 + g * 4;
#pragma unroll
        for (int r = 0; r < 4; ++r)
          C[(size_t)(row + r) * N + col] = acc[mf][nf][r] + bv;
      }
    }
  } else if (MODE == 0) {
    __hip_bfloat16* C = (__hip_bfloat16*)outp;
#pragma unroll
    for (int nf = 0; nf < 4; ++nf) {
      int col = n0 + wn + nf * 16 + l16;
      float bv = bias[col];
      int h = col >> 7, hd = col & 127;
#pragma unroll
      for (int mf = 0; mf < 4; ++mf) {
        int row = m0 + wm + mf * 16 + g * 4;
        int bb = row >> 10, s = row & 1023;
        size_t base = (((size_t)bb * 16 + h) * 1024 + s) * 128 + hd;
#pragma unroll
        for (int r = 0; r < 4; ++r)
          C[base + (size_t)r * 128] = __float2bfloat16(acc[mf][nf][r] + bv);
      }
    }
  } else { // MODE 1: Vt [B,H,HD,S]
    __hip_bfloat16* C = (__hip_bfloat16*)outp;
#pragma unroll
    for (int nf = 0; nf < 4; ++nf) {
      int col = n0 + wn + nf * 16 + l16;
      float bv = bias[col];
      int h = col >> 7, hd = col & 127;
#pragma unroll
      for (int mf = 0; mf < 4; ++mf) {
        int row = m0 + wm + mf * 16 + g * 4;
        int bb = row >> 10, s = row & 1023;   // s multiple of 4
        size_t base = (((size_t)bb * 16 + h) * 128 + hd) * 1024 + s;
        short4v pk;
#pragma unroll
        for (int r = 0; r < 4; ++r) pk[r] = f2b(acc[mf][nf][r] + bv);
        *(short4v*)(C + base) = pk;
      }
    }
  }
}

// ---------------- fused attention ----------------
// 4096 blocks, 256 threads (4 waves), 4 blocks/CU (32KB LDS). bid%8 = XCD; each XCD
// owns 8 heads so co-resident blocks share one head's K/V (512KB, L2-resident).
// Swapped QK^T: mfma(K,Q) -> D[key][qrow]; lane (g,l16) holds 64 P values of q-row l16.
// P staged fp32 in a 32KB LDS buffer in TWO key-halves (waves 0-1 stage half 0,
// waves 2-3 half 1); per half: full-line attn stores + PV accumulation.
__global__ __launch_bounds__(256, 4) void attn_kernel(
    const __hip_bfloat16* __restrict__ Qh,   // [64][1024][128]
    const __hip_bfloat16* __restrict__ Kh,   // [64][1024][128]
    const __hip_bfloat16* __restrict__ Vt,   // [64][128][1024]
    float* __restrict__ attn,                // [64][1024][1024]
    __hip_bfloat16* __restrict__ ctx)        // [4][1024][2048]
{
  __shared__ __align__(16) char Plds[16 * 2048];  // fp32 [16 rows][512 keys], 16B-XOR swizzled
  __shared__ float red[64];

  const int tid = threadIdx.x, lane = tid & 63, w = tid >> 6;
  const int l16 = lane & 15, g = lane >> 4;

  const int bid = blockIdx.x;
  const int xcd = bid & 7, j = bid >> 3;
  const int bh  = xcd * 8 + (j >> 6);      // 8 heads per XCD
  const int q0  = (j & 63) << 4;

  const __hip_bfloat16* Qp = Qh + ((size_t)bh * 1024 + q0) * 128;
  const __hip_bfloat16* Kp = Kh + (size_t)bh * 1024 * 128;
  const __hip_bfloat16* Vp = Vt + (size_t)bh * 128 * 1024;
  float* ap = attn + ((size_t)bh * 1024 + q0) * 1024;

  // Q fragments (B-operand): lane holds Q[l16][g*8 + ds*32 ..]
  bf16x8 qa[4];
#pragma unroll
  for (int ds = 0; ds < 4; ++ds)
    qa[ds] = *(const bf16x8*)(Qp + (size_t)l16 * 128 + ds * 32 + g * 8);

  // GEMM1 swapped: acc[fn] = K_frag x Q_frag -> D[key][qrow]
  f32x4 acc[16];
#pragma unroll
  for (int i = 0; i < 16; ++i) acc[i] = f32x4{0.f, 0.f, 0.f, 0.f};
  const int ncbase = w * 256;
#pragma unroll 4
  for (int fn = 0; fn < 16; ++fn) {
    const __hip_bfloat16* kr = Kp + (size_t)(ncbase + fn * 16 + l16) * 128 + g * 8;
    bf16x8 kb0 = *(const bf16x8*)(kr);
    bf16x8 kb1 = *(const bf16x8*)(kr + 32);
    bf16x8 kb2 = *(const bf16x8*)(kr + 64);
    bf16x8 kb3 = *(const bf16x8*)(kr + 96);
    __builtin_amdgcn_s_setprio(1);
    acc[fn] = __builtin_amdgcn_mfma_f32_16x16x32_bf16(kb0, qa[0], acc[fn], 0, 0, 0);
    acc[fn] = __builtin_amdgcn_mfma_f32_16x16x32_bf16(kb1, qa[1], acc[fn], 0, 0, 0);
    acc[fn] = __builtin_amdgcn_mfma_f32_16x16x32_bf16(kb2, qa[2], acc[fn], 0, 0, 0);
    acc[fn] = __builtin_amdgcn_mfma_f32_16x16x32_bf16(kb3, qa[3], acc[fn], 0, 0, 0);
    __builtin_amdgcn_s_setprio(0);
  }

  // exp (no max-shift: scores ~N(0,0.33), exact fp32 softmax) — all 64 values are row l16
  const float esc = 0.08838834764831845f;   // 1/sqrt(128)
  float s = 0.f;
#pragma unroll
  for (int fn = 0; fn < 16; ++fn)
#pragma unroll
    for (int r = 0; r < 4; ++r) {
      float e = __expf(acc[fn][r] * esc);
      acc[fn][r] = e;
      s += e;
    }
  s += __shfl_xor(s, 16, 64);
  s += __shfl_xor(s, 32, 64);               // wave-partial rowsum (256 keys)
  if (lane < 16) red[w * 16 + l16] = s;
  __syncthreads();
  const float inv = 1.0f / (red[l16] + red[16 + l16] + red[32 + l16] + red[48 + l16]);

  // normalize in registers
#pragma unroll
  for (int fn = 0; fn < 16; ++fn)
#pragma unroll
    for (int r = 0; r < 4; ++r) acc[fn][r] *= inv;

  // PV accumulators: ctx[16][128], wave w owns hd cols [32w, 32w+32)
  f32x4 acc2[2];
  acc2[0] = f32x4{0.f, 0.f, 0.f, 0.f};
  acc2[1] = f32x4{0.f, 0.f, 0.f, 0.f};

  // two key-halves of 512: stage P fp32 -> attn full-line stores -> PV
#pragma unroll
  for (int half = 0; half < 2; ++half) {
    if ((w >> 1) == half) {   // waves 2*half, 2*half+1 stage their 256-key chunks
#pragma unroll
      for (int fn = 0; fn < 16; ++fn) {
        f32x4 pv;
#pragma unroll
        for (int r = 0; r < 4; ++r) pv[r] = acc[fn][r];
        int colb = ((w & 1) * 256 + fn * 16 + g * 4) * 4;   // bytes within half-row
        *(f32x4*)(Plds + l16 * 2048 + (colb ^ ((l16 & 7) << 4))) = pv;
      }
    }
    __syncthreads();

    // attn store: wave w streams rows 4w..4w+3; 256B contiguous per instruction
    {
      const int row = 4 * w + g;
      const char* rp = Plds + row * 2048;
      const int sw = (row & 7) << 4;
      float* apr = ap + (size_t)row * 1024 + half * 512;
#pragma unroll
      for (int it = 0; it < 8; ++it) {
        int colb = it * 256 + l16 * 16;
        f32x4 val = *(const f32x4*)(rp + (colb ^ sw));
        *(f32x4*)(apr + (colb >> 2)) = val;
      }
    }

    // PV for this half: 16 kt steps of 32 keys
    {
      const char* pr = Plds + l16 * 2048;
      const int sw = (l16 & 7) << 4;
#pragma unroll 4
      for (int kt = 0; kt < 16; ++kt) {
        int cb0 = kt * 128 + g * 32;
        f32x4 plo = *(const f32x4*)(pr + (cb0 ^ sw));
        f32x4 phi = *(const f32x4*)(pr + ((cb0 + 16) ^ sw));
        bf16x8 pa;
#pragma unroll
        for (int r = 0; r < 4; ++r) { pa[r] = f2b(plo[r]); pa[4 + r] = f2b(phi[r]); }
        const __hip_bfloat16* vbase = Vp + (size_t)(w * 32 + l16) * 1024 + half * 512 + kt * 32 + g * 8;
        bf16x8 vb0 = *(const bf16x8*)vbase;
        bf16x8 vb1 = *(const bf16x8*)(vbase + 16 * 1024);
        __builtin_amdgcn_s_setprio(1);
        acc2[0] = __builtin_amdgcn_mfma_f32_16x16x32_bf16(pa, vb0, acc2[0], 0, 0, 0);
        acc2[1] = __builtin_amdgcn_mfma_f32_16x16x32_bf16(pa, vb1, acc2[1], 0, 0, 0);
        __builtin_amdgcn_s_setprio(0);
      }
    }
    __syncthreads();   // Plds fully consumed before next half / ctx staging
  }

  // ctx staging: [16][128] bf16 in LDS, then 16B/thread coalesced store
  {
    __hip_bfloat16* cs = (__hip_bfloat16*)Plds;
#pragma unroll
    for (int f2 = 0; f2 < 2; ++f2)
#pragma unroll
      for (int r = 0; r < 4; ++r)
        cs[(g * 4 + r) * 128 + w * 32 + f2 * 16 + l16] = __float2bfloat16(acc2[f2][r]);
    __syncthreads();
    const int row = tid >> 4, c8 = (tid & 15) * 8;
    bf16x8 val = *(const bf16x8*)(cs + row * 128 + c8);
    const int bb = bh >> 4, h = bh & 15;
    *(bf16x8*)(ctx + ((size_t)(bb * 1024 + q0 + row)) * 2048 + h * 128 + c8) = val;
  }
}

extern "C" void kernel_launch(void* const* d_in, const int* in_sizes, int n_in,
                              void* d_out, int out_size, void* d_ws, size_t ws_size,
                              hipStream_t stream) {
  const float* q    = (const float*)d_in[0];
  const float* k    = (const float*)d_in[1];
  const float* v    = (const float*)d_in[2];
  const float* wq_w = (const float*)d_in[3];
  const float* wq_b = (const float*)d_in[4];
  const float* wk_w = (const float*)d_in[5];
  const float* wk_b = (const float*)d_in[6];
  const float* wv_w = (const float*)d_in[7];
  const float* wv_b = (const float*)d_in[8];
  const float* wo_w = (const float*)d_in[9];
  const float* wo_b = (const float*)d_in[10];

  const size_t BSD = (size_t)4 * 1024 * 2048;  // 8388608
  const size_t DD  = (size_t)2048 * 2048;      // 4194304

  float* out  = (float*)d_out;
  float* attn = out + BSD;                     // 67108864 floats

  __hip_bfloat16* qbf = (__hip_bfloat16*)attn; // scratch in not-yet-written attn region
  __hip_bfloat16* kbf = qbf + BSD;
  __hip_bfloat16* vbf = kbf + BSD;

  __hip_bfloat16* wqb = (__hip_bfloat16*)d_ws;
  __hip_bfloat16* wkb = wqb + DD;
  __hip_bfloat16* wvb = wkb + DD;
  __hip_bfloat16* wob = wvb + DD;
  __hip_bfloat16* Qh  = wob + DD;
  __hip_bfloat16* Kh  = Qh + BSD;
  __hip_bfloat16* Vt  = Kh + BSD;
  __hip_bfloat16* ctx = Vt + BSD;

  dim3 cb(256);
  cast_bf16<<<2048, cb, 0, stream>>>(q, qbf, BSD);
  cast_bf16<<<2048, cb, 0, stream>>>(k, kbf, BSD);
  cast_bf16<<<2048, cb, 0, stream>>>(v, vbf, BSD);
  cast_bf16<<<2048, cb, 0, stream>>>(wq_w, wqb, DD);
  cast_bf16<<<2048, cb, 0, stream>>>(wk_w, wkb, DD);
  cast_bf16<<<2048, cb, 0, stream>>>(wv_w, wvb, DD);
  cast_bf16<<<2048, cb, 0, stream>>>(wo_w, wob, DD);

  dim3 gg(16, 32), gb(256);
  gemm_bt<0><<<gg, gb, 0, stream>>>(qbf, wqb, wq_b, Qh, 4096, 2048, 2048);
  gemm_bt<0><<<gg, gb, 0, stream>>>(kbf, wkb, wk_b, Kh, 4096, 2048, 2048);
  gemm_bt<1><<<gg, gb, 0, stream>>>(vbf, wvb, wv_b, Vt, 4096, 2048, 2048);

  attn_kernel<<<dim3(4096), gb, 0, stream>>>(Qh, Kh, Vt, attn, ctx);

  gemm_bt<2><<<gg, gb, 0, stream>>>(ctx, wob, wo_b, out, 4096, 2048, 2048);
}

// Round 4
// 639.310 us; speedup vs baseline: 1.1685x; 1.1685x over previous
//
#include <hip/hip_runtime.h>
#include <hip/hip_bf16.h>

// B=4, S=1024, D=2048, H=16, HD=128. SCALE = sqrt(128).
// d_out = [output fp32 (8388608)] ++ [attn fp32 (67108864)]
// ws layout (bf16): wq,wk,wv,wo [2048*2048 each] | Qh,Kh [B,H,S,HD] | Vt [B,H,HD,S] | ctx [B,S,D]
// attn region of d_out doubles as scratch for bf16 casts of q,k,v (dead before attn kernel writes).

typedef __attribute__((ext_vector_type(4))) float  f32x4;
typedef __attribute__((ext_vector_type(8))) short  bf16x8;   // 8 bf16 in 4 VGPRs
typedef __attribute__((ext_vector_type(4))) short  short4v;
typedef __attribute__((ext_vector_type(8))) short  short8v;

__device__ __forceinline__ short f2b(float f) {
  __hip_bfloat16 h = __float2bfloat16(f);
  return __builtin_bit_cast(short, h);
}

// ---------------- cast fp32 -> bf16, vectorized 8/thread ----------------
__global__ void cast_bf16(const float* __restrict__ in, __hip_bfloat16* __restrict__ out, size_t n) {
  size_t i0 = ((size_t)blockIdx.x * blockDim.x + threadIdx.x) * 8;
  size_t stride = (size_t)gridDim.x * blockDim.x * 8;
  for (size_t i = i0; i < n; i += stride) {
    float4 a = *(const float4*)(in + i);
    float4 b = *(const float4*)(in + i + 4);
    short8v o;
    o[0] = f2b(a.x); o[1] = f2b(a.y); o[2] = f2b(a.z); o[3] = f2b(a.w);
    o[4] = f2b(b.x); o[5] = f2b(b.y); o[6] = f2b(b.z); o[7] = f2b(b.w);
    *(short8v*)(out + i) = o;
  }
}

// ---------------- async global->LDS, 16B per lane ----------------
__device__ __forceinline__ void gload_lds16(const __hip_bfloat16* g, char* l) {
  __builtin_amdgcn_global_load_lds(
      (const __attribute__((address_space(1))) unsigned int*)g,
      (__attribute__((address_space(3))) unsigned int*)l, 16, 0, 0);
}

// ---------------- GEMM: C[m,n] = sum_k A[m,k]*Bt[n,k] + bias[n] ----------------
// m97 structure: 128x128 tile, 4 waves (each 64x64), BK=32, 16x16x32 bf16 MFMA.
// MODE 0: out bf16 to [B=4,H=16,S=1024,HD=128]   (Q,K heads)
// MODE 1: out bf16 to [B,H,HD,S] (V transposed)
// MODE 2: out fp32 row-major [M][N]              (final output)
template<int MODE>
__global__ __launch_bounds__(256, 2) void gemm_bt(
    const __hip_bfloat16* __restrict__ A,
    const __hip_bfloat16* __restrict__ Bt,
    const float* __restrict__ bias,
    void* __restrict__ outp,
    int M, int N, int K)
{
  __shared__ __align__(16) char As[128 * 64];  // 128 rows x 32 bf16
  __shared__ __align__(16) char Bs[128 * 64];
  const int tid  = threadIdx.x;
  const int lane = tid & 63, wid = tid >> 6;
  const int l16  = lane & 15, g = lane >> 4;
  const int m0 = blockIdx.y * 128, n0 = blockIdx.x * 128;
  const int wm = (wid >> 1) * 64, wn = (wid & 1) * 64;
  const size_t Kz = (size_t)K;

  f32x4 acc[4][4];
#pragma unroll
  for (int i = 0; i < 4; ++i)
#pragma unroll
    for (int j = 0; j < 4; ++j) acc[i][j] = f32x4{0.f, 0.f, 0.f, 0.f};

  const __hip_bfloat16* ga0 = A  + (size_t)(m0 + wid * 32 + (lane >> 2)) * Kz + (lane & 3) * 8;
  const __hip_bfloat16* gb0 = Bt + (size_t)(n0 + wid * 32 + (lane >> 2)) * Kz + (lane & 3) * 8;
  char* lA0 = As + wid * 2048;
  char* lB0 = Bs + wid * 2048;

  const int nk = K >> 5;
  for (int kt = 0; kt < nk; ++kt) {
    __syncthreads();
    gload_lds16(ga0,            lA0);
    gload_lds16(ga0 + 16 * Kz,  lA0 + 1024);
    gload_lds16(gb0,            lB0);
    gload_lds16(gb0 + 16 * Kz,  lB0 + 1024);
    ga0 += 32; gb0 += 32;
    asm volatile("s_waitcnt vmcnt(0)" ::: "memory");
    __syncthreads();
    bf16x8 a[4], b[4];
#pragma unroll
    for (int mf = 0; mf < 4; ++mf)
      a[mf] = *(const bf16x8*)(As + (wm + mf * 16 + l16) * 64 + g * 16);
#pragma unroll
    for (int nf = 0; nf < 4; ++nf)
      b[nf] = *(const bf16x8*)(Bs + (wn + nf * 16 + l16) * 64 + g * 16);
#pragma unroll
    for (int mf = 0; mf < 4; ++mf)
#pragma unroll
      for (int nf = 0; nf < 4; ++nf)
        acc[mf][nf] = __builtin_amdgcn_mfma_f32_16x16x32_bf16(a[mf], b[nf], acc[mf][nf], 0, 0, 0);
  }

  if (MODE == 2) {
    float* C = (float*)outp;
#pragma unroll
    for (int nf = 0; nf < 4; ++nf) {
      int col = n0 + wn + nf * 16 + l16;
      float bv = bias[col];
#pragma unroll
      for (int mf = 0; mf < 4; ++mf) {
        int row = m0 + wm + mf * 16 + g * 4;
#pragma unroll
        for (int r = 0; r < 4; ++r)
          C[(size_t)(row + r) * N + col] = acc[mf][nf][r] + bv;
      }
    }
  } else if (MODE == 0) {
    __hip_bfloat16* C = (__hip_bfloat16*)outp;
#pragma unroll
    for (int nf = 0; nf < 4; ++nf) {
      int col = n0 + wn + nf * 16 + l16;
      float bv = bias[col];
      int h = col >> 7, hd = col & 127;
#pragma unroll
      for (int mf = 0; mf < 4; ++mf) {
        int row = m0 + wm + mf * 16 + g * 4;
        int bb = row >> 10, s = row & 1023;
        size_t base = (((size_t)bb * 16 + h) * 1024 + s) * 128 + hd;
#pragma unroll
        for (int r = 0; r < 4; ++r)
          C[base + (size_t)r * 128] = __float2bfloat16(acc[mf][nf][r] + bv);
      }
    }
  } else { // MODE 1: Vt [B,H,HD,S]
    __hip_bfloat16* C = (__hip_bfloat16*)outp;
#pragma unroll
    for (int nf = 0; nf < 4; ++nf) {
      int col = n0 + wn + nf * 16 + l16;
      float bv = bias[col];
      int h = col >> 7, hd = col & 127;
#pragma unroll
      for (int mf = 0; mf < 4; ++mf) {
        int row = m0 + wm + mf * 16 + g * 4;
        int bb = row >> 10, s = row & 1023;   // s multiple of 4
        size_t base = (((size_t)bb * 16 + h) * 128 + hd) * 1024 + s;
        short4v pk;
#pragma unroll
        for (int r = 0; r < 4; ++r) pk[r] = f2b(acc[mf][nf][r] + bv);
        *(short4v*)(C + base) = pk;
      }
    }
  }
}

// ---------------- fused attention ----------------
// 4096 blocks, 256 threads (4 waves), ~4 blocks/CU (33KB LDS). bid%8 = XCD; each XCD
// owns 8 heads so co-resident blocks share 1-2 heads' K/V (<=1MB, L2-resident).
// Swapped QK^T: mfma(K,Q) -> D[key][qrow]; lane (g,l16) holds 64 P values of q-row l16.
// attn written DIRECTLY from registers (nontemporal f32x4, 64B/row/instr);
// P staged as bf16 in 32KB XOR-swizzled LDS for the PV MFMA A-operand.
__global__ __launch_bounds__(256, 4) void attn_kernel(
    const __hip_bfloat16* __restrict__ Qh,   // [64][1024][128]
    const __hip_bfloat16* __restrict__ Kh,   // [64][1024][128]
    const __hip_bfloat16* __restrict__ Vt,   // [64][128][1024]
    float* __restrict__ attn,                // [64][1024][1024]
    __hip_bfloat16* __restrict__ ctx)        // [4][1024][2048]
{
  __shared__ __align__(16) char Plds[16 * 2048];  // bf16 [16 rows][1024 keys], 16B-XOR swizzled
  __shared__ float red[64];

  const int tid = threadIdx.x, lane = tid & 63, w = tid >> 6;
  const int l16 = lane & 15, g = lane >> 4;

  const int bid = blockIdx.x;
  const int xcd = bid & 7, j = bid >> 3;
  const int bh  = xcd * 8 + (j >> 6);      // 8 heads per XCD
  const int q0  = (j & 63) << 4;

  const __hip_bfloat16* Qp = Qh + ((size_t)bh * 1024 + q0) * 128;
  const __hip_bfloat16* Kp = Kh + (size_t)bh * 1024 * 128;
  const __hip_bfloat16* Vp = Vt + (size_t)bh * 128 * 1024;
  float* ap = attn + ((size_t)bh * 1024 + q0) * 1024;

  // Q fragments (B-operand): lane holds Q[l16][g*8 + ds*32 ..]
  bf16x8 qa[4];
#pragma unroll
  for (int ds = 0; ds < 4; ++ds)
    qa[ds] = *(const bf16x8*)(Qp + (size_t)l16 * 128 + ds * 32 + g * 8);

  // GEMM1 swapped: acc[fn] = K_frag x Q_frag -> D[key][qrow]
  f32x4 acc[16];
#pragma unroll
  for (int i = 0; i < 16; ++i) acc[i] = f32x4{0.f, 0.f, 0.f, 0.f};
  const int ncbase = w * 256;
#pragma unroll 4
  for (int fn = 0; fn < 16; ++fn) {
    const __hip_bfloat16* kr = Kp + (size_t)(ncbase + fn * 16 + l16) * 128 + g * 8;
    bf16x8 kb0 = *(const bf16x8*)(kr);
    bf16x8 kb1 = *(const bf16x8*)(kr + 32);
    bf16x8 kb2 = *(const bf16x8*)(kr + 64);
    bf16x8 kb3 = *(const bf16x8*)(kr + 96);
    __builtin_amdgcn_s_setprio(1);
    acc[fn] = __builtin_amdgcn_mfma_f32_16x16x32_bf16(kb0, qa[0], acc[fn], 0, 0, 0);
    acc[fn] = __builtin_amdgcn_mfma_f32_16x16x32_bf16(kb1, qa[1], acc[fn], 0, 0, 0);
    acc[fn] = __builtin_amdgcn_mfma_f32_16x16x32_bf16(kb2, qa[2], acc[fn], 0, 0, 0);
    acc[fn] = __builtin_amdgcn_mfma_f32_16x16x32_bf16(kb3, qa[3], acc[fn], 0, 0, 0);
    __builtin_amdgcn_s_setprio(0);
  }

  // exp (no max-shift: scores ~N(0,0.33), exact fp32 softmax) — all 64 values are row l16
  const float esc = 0.08838834764831845f;   // 1/sqrt(128)
  float s = 0.f;
#pragma unroll
  for (int fn = 0; fn < 16; ++fn)
#pragma unroll
    for (int r = 0; r < 4; ++r) {
      float e = __expf(acc[fn][r] * esc);
      acc[fn][r] = e;
      s += e;
    }
  s += __shfl_xor(s, 16, 64);
  s += __shfl_xor(s, 32, 64);               // wave-partial rowsum (256 keys)
  if (lane < 16) red[w * 16 + l16] = s;
  __syncthreads();
  const float inv = 1.0f / (red[l16] + red[16 + l16] + red[32 + l16] + red[48 + l16]);

  // normalize; attn store straight from registers (NT, keeps L2 clean for K/V);
  // stage bf16 P into swizzled LDS (8B ds_write per lane per fn)
  const int swl = (l16 & 7) << 4;
#pragma unroll
  for (int fn = 0; fn < 16; ++fn) {
    int col = ncbase + fn * 16 + g * 4;
    f32x4 pv;
#pragma unroll
    for (int r = 0; r < 4; ++r) pv[r] = acc[fn][r] * inv;
    __builtin_nontemporal_store(pv, (f32x4*)(ap + (size_t)l16 * 1024 + col));
    short4v pb;
#pragma unroll
    for (int r = 0; r < 4; ++r) pb[r] = f2b(pv[r]);
    *(short4v*)(Plds + l16 * 2048 + ((col * 2) ^ swl)) = pb;
  }
  __syncthreads();

  // PV: ctx[16][128] = P[16][1024] @ V^T; wave w owns hd cols [32w, 32w+32)
  f32x4 acc2[2];
  acc2[0] = f32x4{0.f, 0.f, 0.f, 0.f};
  acc2[1] = f32x4{0.f, 0.f, 0.f, 0.f};
  {
    const char* pr = Plds + l16 * 2048;
#pragma unroll 4
    for (int kt = 0; kt < 32; ++kt) {
      bf16x8 pa = *(const bf16x8*)(pr + ((kt * 64 + g * 16) ^ swl));
      const __hip_bfloat16* vbase = Vp + (size_t)(w * 32 + l16) * 1024 + kt * 32 + g * 8;
      bf16x8 vb0 = *(const bf16x8*)vbase;
      bf16x8 vb1 = *(const bf16x8*)(vbase + 16 * 1024);
      __builtin_amdgcn_s_setprio(1);
      acc2[0] = __builtin_amdgcn_mfma_f32_16x16x32_bf16(pa, vb0, acc2[0], 0, 0, 0);
      acc2[1] = __builtin_amdgcn_mfma_f32_16x16x32_bf16(pa, vb1, acc2[1], 0, 0, 0);
      __builtin_amdgcn_s_setprio(0);
    }
  }
  __syncthreads();   // Plds fully consumed before ctx staging

  // ctx staging: [16][128] bf16 in LDS, then 16B/thread coalesced store
  {
    __hip_bfloat16* cs = (__hip_bfloat16*)Plds;
#pragma unroll
    for (int f2 = 0; f2 < 2; ++f2)
#pragma unroll
      for (int r = 0; r < 4; ++r)
        cs[(g * 4 + r) * 128 + w * 32 + f2 * 16 + l16] = __float2bfloat16(acc2[f2][r]);
    __syncthreads();
    const int row = tid >> 4, c8 = (tid & 15) * 8;
    bf16x8 val = *(const bf16x8*)(cs + row * 128 + c8);
    const int bb = bh >> 4, h = bh & 15;
    *(bf16x8*)(ctx + ((size_t)(bb * 1024 + q0 + row)) * 2048 + h * 128 + c8) = val;
  }
}

extern "C" void kernel_launch(void* const* d_in, const int* in_sizes, int n_in,
                              void* d_out, int out_size, void* d_ws, size_t ws_size,
                              hipStream_t stream) {
  const float* q    = (const float*)d_in[0];
  const float* k    = (const float*)d_in[1];
  const float* v    = (const float*)d_in[2];
  const float* wq_w = (const float*)d_in[3];
  const float* wq_b = (const float*)d_in[4];
  const float* wk_w = (const float*)d_in[5];
  const float* wk_b = (const float*)d_in[6];
  const float* wv_w = (const float*)d_in[7];
  const float* wv_b = (const float*)d_in[8];
  const float* wo_w = (const float*)d_in[9];
  const float* wo_b = (const float*)d_in[10];

  const size_t BSD = (size_t)4 * 1024 * 2048;  // 8388608
  const size_t DD  = (size_t)2048 * 2048;      // 4194304

  float* out  = (float*)d_out;
  float* attn = out + BSD;                     // 67108864 floats

  __hip_bfloat16* qbf = (__hip_bfloat16*)attn; // scratch in not-yet-written attn region
  __hip_bfloat16* kbf = qbf + BSD;
  __hip_bfloat16* vbf = kbf + BSD;

  __hip_bfloat16* wqb = (__hip_bfloat16*)d_ws;
  __hip_bfloat16* wkb = wqb + DD;
  __hip_bfloat16* wvb = wkb + DD;
  __hip_bfloat16* wob = wvb + DD;
  __hip_bfloat16* Qh  = wob + DD;
  __hip_bfloat16* Kh  = Qh + BSD;
  __hip_bfloat16* Vt  = Kh + BSD;
  __hip_bfloat16* ctx = Vt + BSD;

  dim3 cb(256);
  cast_bf16<<<2048, cb, 0, stream>>>(q, qbf, BSD);
  cast_bf16<<<2048, cb, 0, stream>>>(k, kbf, BSD);
  cast_bf16<<<2048, cb, 0, stream>>>(v, vbf, BSD);
  cast_bf16<<<2048, cb, 0, stream>>>(wq_w, wqb, DD);
  cast_bf16<<<2048, cb, 0, stream>>>(wk_w, wkb, DD);
  cast_bf16<<<2048, cb, 0, stream>>>(wv_w, wvb, DD);
  cast_bf16<<<2048, cb, 0, stream>>>(wo_w, wob, DD);

  dim3 gg(16, 32), gb(256);
  gemm_bt<0><<<gg, gb, 0, stream>>>(qbf, wqb, wq_b, Qh, 4096, 2048, 2048);
  gemm_bt<0><<<gg, gb, 0, stream>>>(kbf, wkb, wk_b, Kh, 4096, 2048, 2048);
  gemm_bt<1><<<gg, gb, 0, stream>>>(vbf, wvb, wv_b, Vt, 4096, 2048, 2048);

  attn_kernel<<<dim3(4096), gb, 0, stream>>>(Qh, Kh, Vt, attn, ctx);

  gemm_bt<2><<<gg, gb, 0, stream>>>(ctx, wob, wo_b, out, 4096, 2048, 2048);
}

// Round 5
// 411.017 us; speedup vs baseline: 1.8175x; 1.5554x over previous
//
#include <hip/hip_runtime.h>
#include <hip/hip_bf16.h>

// B=4, S=1024, D=2048, H=16, HD=128. SCALE = sqrt(128).
// d_out = [output fp32 (8388608)] ++ [attn fp32 (67108864)]
// ws layout (bf16): wq,wk,wv,wo [2048*2048 each] | Qh,Kh [B,H,S,HD] | Vt [B,H,HD,S] | ctx [B,S,D]
// attn region of d_out doubles as scratch for bf16 casts of q,k,v (dead before attn kernel writes).

typedef __attribute__((ext_vector_type(4)))  float f32x4;
typedef __attribute__((ext_vector_type(16))) float f32x16;
typedef __attribute__((ext_vector_type(8))) short  bf16x8;   // 8 bf16 in 4 VGPRs
typedef __attribute__((ext_vector_type(4))) short  short4v;
typedef __attribute__((ext_vector_type(8))) short  short8v;

__device__ __forceinline__ short f2b(float f) {
  __hip_bfloat16 h = __float2bfloat16(f);
  return __builtin_bit_cast(short, h);
}
__device__ __forceinline__ float b2f(short s) {
  __hip_bfloat16 h = __builtin_bit_cast(__hip_bfloat16, s);
  return __bfloat162float(h);
}

// ---------------- cast fp32 -> bf16, vectorized 8/thread ----------------
__global__ void cast_bf16(const float* __restrict__ in, __hip_bfloat16* __restrict__ out, size_t n) {
  size_t i0 = ((size_t)blockIdx.x * blockDim.x + threadIdx.x) * 8;
  size_t stride = (size_t)gridDim.x * blockDim.x * 8;
  for (size_t i = i0; i < n; i += stride) {
    float4 a = *(const float4*)(in + i);
    float4 b = *(const float4*)(in + i + 4);
    short8v o;
    o[0] = f2b(a.x); o[1] = f2b(a.y); o[2] = f2b(a.z); o[3] = f2b(a.w);
    o[4] = f2b(b.x); o[5] = f2b(b.y); o[6] = f2b(b.z); o[7] = f2b(b.w);
    *(short8v*)(out + i) = o;
  }
}

// ---------------- async global->LDS, 16B per lane ----------------
__device__ __forceinline__ void gload_lds16(const __hip_bfloat16* g, char* l) {
  __builtin_amdgcn_global_load_lds(
      (const __attribute__((address_space(1))) unsigned int*)g,
      (__attribute__((address_space(3))) unsigned int*)l, 16, 0, 0);
}

// ---------------- GEMM: C[m,n] = sum_k A[m,k]*Bt[n,k] + bias[n] ----------------
// m97 structure: 128x128 tile, 4 waves (each 64x64), BK=32, 16x16x32 bf16 MFMA.
// MODE 0: out bf16 to [B=4,H=16,S=1024,HD=128]   (Q,K heads)
// MODE 1: out bf16 to [B,H,HD,S] (V transposed)
// MODE 2: out fp32 row-major [M][N]              (final output)
template<int MODE>
__global__ __launch_bounds__(256, 2) void gemm_bt(
    const __hip_bfloat16* __restrict__ A,
    const __hip_bfloat16* __restrict__ Bt,
    const float* __restrict__ bias,
    void* __restrict__ outp,
    int M, int N, int K)
{
  __shared__ __align__(16) char As[128 * 64];  // 128 rows x 32 bf16
  __shared__ __align__(16) char Bs[128 * 64];
  const int tid  = threadIdx.x;
  const int lane = tid & 63, wid = tid >> 6;
  const int l16  = lane & 15, g = lane >> 4;
  const int m0 = blockIdx.y * 128, n0 = blockIdx.x * 128;
  const int wm = (wid >> 1) * 64, wn = (wid & 1) * 64;
  const size_t Kz = (size_t)K;

  f32x4 acc[4][4];
#pragma unroll
  for (int i = 0; i < 4; ++i)
#pragma unroll
    for (int j = 0; j < 4; ++j) acc[i][j] = f32x4{0.f, 0.f, 0.f, 0.f};

  const __hip_bfloat16* ga0 = A  + (size_t)(m0 + wid * 32 + (lane >> 2)) * Kz + (lane & 3) * 8;
  const __hip_bfloat16* gb0 = Bt + (size_t)(n0 + wid * 32 + (lane >> 2)) * Kz + (lane & 3) * 8;
  char* lA0 = As + wid * 2048;
  char* lB0 = Bs + wid * 2048;

  const int nk = K >> 5;
  for (int kt = 0; kt < nk; ++kt) {
    __syncthreads();
    gload_lds16(ga0,            lA0);
    gload_lds16(ga0 + 16 * Kz,  lA0 + 1024);
    gload_lds16(gb0,            lB0);
    gload_lds16(gb0 + 16 * Kz,  lB0 + 1024);
    ga0 += 32; gb0 += 32;
    asm volatile("s_waitcnt vmcnt(0)" ::: "memory");
    __syncthreads();
    bf16x8 a[4], b[4];
#pragma unroll
    for (int mf = 0; mf < 4; ++mf)
      a[mf] = *(const bf16x8*)(As + (wm + mf * 16 + l16) * 64 + g * 16);
#pragma unroll
    for (int nf = 0; nf < 4; ++nf)
      b[nf] = *(const bf16x8*)(Bs + (wn + nf * 16 + l16) * 64 + g * 16);
#pragma unroll
    for (int mf = 0; mf < 4; ++mf)
#pragma unroll
      for (int nf = 0; nf < 4; ++nf)
        acc[mf][nf] = __builtin_amdgcn_mfma_f32_16x16x32_bf16(a[mf], b[nf], acc[mf][nf], 0, 0, 0);
  }

  if (MODE == 2) {
    float* C = (float*)outp;
#pragma unroll
    for (int nf = 0; nf < 4; ++nf) {
      int col = n0 + wn + nf * 16 + l16;
      float bv = bias[col];
#pragma unroll
      for (int mf = 0; mf < 4; ++mf) {
        int row = m0 + wm + mf * 16 + g * 4;
#pragma unroll
        for (int r = 0; r < 4; ++r)
          C[(size_t)(row + r) * N + col] = acc[mf][nf][r] + bv;
      }
    }
  } else if (MODE == 0) {
    __hip_bfloat16* C = (__hip_bfloat16*)outp;
#pragma unroll
    for (int nf = 0; nf < 4; ++nf) {
      int col = n0 + wn + nf * 16 + l16;
      float bv = bias[col];
      int h = col >> 7, hd = col & 127;
#pragma unroll
      for (int mf = 0; mf < 4; ++mf) {
        int row = m0 + wm + mf * 16 + g * 4;
        int bb = row >> 10, s = row & 1023;
        size_t base = (((size_t)bb * 16 + h) * 1024 + s) * 128 + hd;
#pragma unroll
        for (int r = 0; r < 4; ++r)
          C[base + (size_t)r * 128] = __float2bfloat16(acc[mf][nf][r] + bv);
      }
    }
  } else { // MODE 1: Vt [B,H,HD,S]
    __hip_bfloat16* C = (__hip_bfloat16*)outp;
#pragma unroll
    for (int nf = 0; nf < 4; ++nf) {
      int col = n0 + wn + nf * 16 + l16;
      float bv = bias[col];
      int h = col >> 7, hd = col & 127;
#pragma unroll
      for (int mf = 0; mf < 4; ++mf) {
        int row = m0 + wm + mf * 16 + g * 4;
        int bb = row >> 10, s = row & 1023;   // s multiple of 4
        size_t base = (((size_t)bb * 16 + h) * 128 + hd) * 1024 + s;
        short4v pk;
#pragma unroll
        for (int r = 0; r < 4; ++r) pk[r] = f2b(acc[mf][nf][r] + bv);
        *(short4v*)(C + base) = pk;
      }
    }
  }
}

// ---------------- fused attention, QBLK=32, 8 waves, 32x32 MFMA QK^T ----------------
// 2048 blocks x 512 threads, 2 blocks/CU (66.7KB LDS). bid%8 = XCD (8 heads each).
// Per block: 32 q rows x 1024 keys. QK^T swapped mfma32(K,Q): 4 passes; pass p, wave w
// computes keys [p*256+w*32, +32) x all 32 q rows in ONE 32x32 frag (16 VGPR).
// P = exp(score) stored UNNORMALIZED bf16 in swizzled LDS; row-sums reduced lane-local
// + cross-wave; normalization folded into attn-store (x inv) and final ctx scale.
__global__ __launch_bounds__(512, 4) void attn_kernel(
    const __hip_bfloat16* __restrict__ Qh,   // [64][1024][128]
    const __hip_bfloat16* __restrict__ Kh,   // [64][1024][128]
    const __hip_bfloat16* __restrict__ Vt,   // [64][128][1024]
    float* __restrict__ attn,                // [64][1024][1024]
    __hip_bfloat16* __restrict__ ctx)        // [4][1024][2048]
{
  __shared__ __align__(16) char Plds[32 * 2048];  // bf16 [32 rows][1024 keys], 16B-XOR swizzled
  __shared__ float red[8 * 32];
  __shared__ float invs[32];

  const int tid = threadIdx.x, lane = tid & 63, w = tid >> 6;
  const int l16 = lane & 15, g = lane >> 4;
  const int l31 = lane & 31, kh = lane >> 5;

  const int bid = blockIdx.x;
  const int xcd = bid & 7, j = bid >> 3;          // j in 0..255
  const int bh  = xcd * 8 + (j >> 5);             // 8 heads per XCD
  const int q0  = (j & 31) << 5;                  // 32-row q tile

  const __hip_bfloat16* Qp = Qh + ((size_t)bh * 1024 + q0) * 128;
  const __hip_bfloat16* Kp = Kh + (size_t)bh * 1024 * 128;
  const __hip_bfloat16* Vp = Vt + (size_t)bh * 128 * 1024;
  float* ap = attn + ((size_t)bh * 1024 + q0) * 1024;

  // Q B-frags for 32x32x16: lane holds Q[q0+l31][kh*8 + s*16 ..+8]
  bf16x8 qb[8];
#pragma unroll
  for (int s = 0; s < 8; ++s)
    qb[s] = *(const bf16x8*)(Qp + (size_t)l31 * 128 + s * 16 + kh * 8);

  const float esc = 0.08838834764831845f;   // 1/sqrt(128)
  float rs = 0.f;                           // row-sum partial for qrow l31

  // GEMM1: 4 passes; D[key][qrow]: col=l31 (qrow), row=(reg&3)+8*(reg>>2)+4*kh
#pragma unroll
  for (int pass = 0; pass < 4; ++pass) {
    const int keybase = pass * 256 + w * 32;
    const __hip_bfloat16* kr = Kp + (size_t)(keybase + l31) * 128 + kh * 8;
    bf16x8 kb[8];
#pragma unroll
    for (int s = 0; s < 8; ++s) kb[s] = *(const bf16x8*)(kr + s * 16);
    f32x16 acc;
#pragma unroll
    for (int i = 0; i < 16; ++i) acc[i] = 0.f;
    __builtin_amdgcn_s_setprio(1);
#pragma unroll
    for (int s = 0; s < 8; ++s)
      acc = __builtin_amdgcn_mfma_f32_32x32x16_bf16(kb[s], qb[s], acc, 0, 0, 0);
    __builtin_amdgcn_s_setprio(0);
    // exp, accumulate row-sum, write unnormalized bf16 P to swizzled LDS
#pragma unroll
    for (int grp = 0; grp < 4; ++grp) {
      short4v pk;
#pragma unroll
      for (int jj = 0; jj < 4; ++jj) {
        float e = __expf(acc[grp * 4 + jj] * esc);
        rs += e;
        pk[jj] = f2b(e);
      }
      int key0 = keybase + grp * 8 + kh * 4;
      *(short4v*)(Plds + l31 * 2048 + ((key0 * 2) ^ ((l31 & 7) << 4))) = pk;
    }
  }
  rs += __shfl_xor(rs, 32, 64);             // full 128-key partial for qrow l31
  if (lane < 32) red[w * 32 + l31] = rs;
  __syncthreads();
  if (tid < 32) {
    float t = 0.f;
#pragma unroll
    for (int ww = 0; ww < 8; ++ww) t += red[ww * 32 + tid];
    invs[tid] = 1.0f / t;
  }
  __syncthreads();

  // attn store: wave w streams rows 4w..4w+3 (x inv), NT, 256B contiguous per row chunk
  {
    const int row = 4 * w + g;
    const float invr = invs[row];
    const char* rp = Plds + row * 2048;
    const int sw = (row & 7) << 4;
    float* apr = ap + (size_t)row * 1024;
#pragma unroll
    for (int it = 0; it < 16; ++it) {
      int col = it * 64 + l16 * 4;
      short4v pb = *(const short4v*)(rp + ((col * 2) ^ sw));
      f32x4 val;
#pragma unroll
      for (int r = 0; r < 4; ++r) val[r] = b2f(pb[r]) * invr;
      __builtin_nontemporal_store(val, (f32x4*)(apr + col));
    }
  }

  // PV: ctx[32][128] = P[32][1024] @ V^T (unnormalized); wave w owns hd [16w,16w+16)
  f32x4 acc2[2];
  acc2[0] = f32x4{0.f, 0.f, 0.f, 0.f};
  acc2[1] = f32x4{0.f, 0.f, 0.f, 0.f};
  {
    const char* pr0 = Plds + l16 * 2048;            // qfrag 0 rows 0..15
    const char* pr1 = Plds + (16 + l16) * 2048;     // qfrag 1 rows 16..31
    const int sw = (l16 & 7) << 4;
#pragma unroll 4
    for (int kt = 0; kt < 32; ++kt) {
      int cb = (kt * 64 + g * 16) ^ sw;
      bf16x8 pa0 = *(const bf16x8*)(pr0 + cb);
      bf16x8 pa1 = *(const bf16x8*)(pr1 + cb);
      const __hip_bfloat16* vr = Vp + (size_t)(16 * w + l16) * 1024 + kt * 32 + g * 8;
      bf16x8 vb = *(const bf16x8*)vr;
      __builtin_amdgcn_s_setprio(1);
      acc2[0] = __builtin_amdgcn_mfma_f32_16x16x32_bf16(pa0, vb, acc2[0], 0, 0, 0);
      acc2[1] = __builtin_amdgcn_mfma_f32_16x16x32_bf16(pa1, vb, acc2[1], 0, 0, 0);
      __builtin_amdgcn_s_setprio(0);
    }
  }
  __syncthreads();   // Plds fully consumed

  // ctx staging with deferred normalization: [32][128] bf16 in LDS, then coalesced store
  {
    __hip_bfloat16* cs = (__hip_bfloat16*)Plds;
#pragma unroll
    for (int t = 0; t < 2; ++t) {
      f32x4 iv = *(const f32x4*)(invs + t * 16 + g * 4);
#pragma unroll
      for (int r = 0; r < 4; ++r)
        cs[(t * 16 + g * 4 + r) * 128 + 16 * w + l16] = __float2bfloat16(acc2[t][r] * iv[r]);
    }
    __syncthreads();
    const int row = tid >> 4, c8 = (tid & 15) * 8;   // 32 rows x 128 cols
    bf16x8 val = *(const bf16x8*)(cs + row * 128 + c8);
    const int bb = bh >> 4, h = bh & 15;
    *(bf16x8*)(ctx + ((size_t)(bb * 1024 + q0 + row)) * 2048 + h * 128 + c8) = val;
  }
}

extern "C" void kernel_launch(void* const* d_in, const int* in_sizes, int n_in,
                              void* d_out, int out_size, void* d_ws, size_t ws_size,
                              hipStream_t stream) {
  const float* q    = (const float*)d_in[0];
  const float* k    = (const float*)d_in[1];
  const float* v    = (const float*)d_in[2];
  const float* wq_w = (const float*)d_in[3];
  const float* wq_b = (const float*)d_in[4];
  const float* wk_w = (const float*)d_in[5];
  const float* wk_b = (const float*)d_in[6];
  const float* wv_w = (const float*)d_in[7];
  const float* wv_b = (const float*)d_in[8];
  const float* wo_w = (const float*)d_in[9];
  const float* wo_b = (const float*)d_in[10];

  const size_t BSD = (size_t)4 * 1024 * 2048;  // 8388608
  const size_t DD  = (size_t)2048 * 2048;      // 4194304

  float* out  = (float*)d_out;
  float* attn = out + BSD;                     // 67108864 floats

  __hip_bfloat16* qbf = (__hip_bfloat16*)attn; // scratch in not-yet-written attn region
  __hip_bfloat16* kbf = qbf + BSD;
  __hip_bfloat16* vbf = kbf + BSD;

  __hip_bfloat16* wqb = (__hip_bfloat16*)d_ws;
  __hip_bfloat16* wkb = wqb + DD;
  __hip_bfloat16* wvb = wkb + DD;
  __hip_bfloat16* wob = wvb + DD;
  __hip_bfloat16* Qh  = wob + DD;
  __hip_bfloat16* Kh  = Qh + BSD;
  __hip_bfloat16* Vt  = Kh + BSD;
  __hip_bfloat16* ctx = Vt + BSD;

  dim3 cb(256);
  cast_bf16<<<2048, cb, 0, stream>>>(q, qbf, BSD);
  cast_bf16<<<2048, cb, 0, stream>>>(k, kbf, BSD);
  cast_bf16<<<2048, cb, 0, stream>>>(v, vbf, BSD);
  cast_bf16<<<2048, cb, 0, stream>>>(wq_w, wqb, DD);
  cast_bf16<<<2048, cb, 0, stream>>>(wk_w, wkb, DD);
  cast_bf16<<<2048, cb, 0, stream>>>(wv_w, wvb, DD);
  cast_bf16<<<2048, cb, 0, stream>>>(wo_w, wob, DD);

  dim3 gg(16, 32), gb(256);
  gemm_bt<0><<<gg, gb, 0, stream>>>(qbf, wqb, wq_b, Qh, 4096, 2048, 2048);
  gemm_bt<0><<<gg, gb, 0, stream>>>(kbf, wkb, wk_b, Kh, 4096, 2048, 2048);
  gemm_bt<1><<<gg, gb, 0, stream>>>(vbf, wvb, wv_b, Vt, 4096, 2048, 2048);

  attn_kernel<<<dim3(2048), dim3(512), 0, stream>>>(Qh, Kh, Vt, attn, ctx);

  gemm_bt<2><<<gg, gb, 0, stream>>>(ctx, wob, wo_b, out, 4096, 2048, 2048);
}

// Round 6
// 379.601 us; speedup vs baseline: 1.9679x; 1.0828x over previous
//
#include <hip/hip_runtime.h>
#include <hip/hip_bf16.h>

// B=4, S=1024, D=2048, H=16, HD=128. SCALE = sqrt(128).
// d_out = [output fp32 (8388608)] ++ [attn fp32 (67108864)]
// ws layout (bf16): wq,wk,wv,wo [2048*2048 each] | Qh,Kh [B,H,S,HD] | Vt [B,H,HD,S] | ctx [B,S,D]
// attn region of d_out doubles as scratch for bf16 casts of q,k,v (dead before attn kernel writes).

typedef __attribute__((ext_vector_type(4)))  float f32x4;
typedef __attribute__((ext_vector_type(16))) float f32x16;
typedef __attribute__((ext_vector_type(8))) short  bf16x8;   // 8 bf16 in 4 VGPRs
typedef __attribute__((ext_vector_type(4))) short  short4v;
typedef __attribute__((ext_vector_type(8))) short  short8v;

__device__ __forceinline__ short f2b(float f) {
  __hip_bfloat16 h = __float2bfloat16(f);
  return __builtin_bit_cast(short, h);
}
__device__ __forceinline__ float b2f(short s) {
  __hip_bfloat16 h = __builtin_bit_cast(__hip_bfloat16, s);
  return __bfloat162float(h);
}

// ---------------- fused cast fp32->bf16 for all 7 arrays, one launch ----------------
// segments: q,k,v (8388608 each = 2^20 chunks of 8), wq,wk,wv,wo (4194304 = 2^19 chunks).
// total chunks = 3*2^20 + 4*2^19 = 5242880 = 524288 threads x 10 iters.
__global__ void cast_all(
    const float* __restrict__ q,  const float* __restrict__ k,  const float* __restrict__ v,
    const float* __restrict__ w0, const float* __restrict__ w1, const float* __restrict__ w2,
    const float* __restrict__ w3,
    __hip_bfloat16* __restrict__ qd, __hip_bfloat16* __restrict__ kd, __hip_bfloat16* __restrict__ vd,
    __hip_bfloat16* __restrict__ d0, __hip_bfloat16* __restrict__ d1, __hip_bfloat16* __restrict__ d2,
    __hip_bfloat16* __restrict__ d3)
{
  const int c0 = blockIdx.x * blockDim.x + threadIdx.x;   // 524288 threads
#pragma unroll
  for (int it = 0; it < 10; ++it) {
    int c = c0 + it * 524288;
    const float* in; __hip_bfloat16* out; size_t off;
    if (c < 3145728) {
      int seg = c >> 20; off = (size_t)(c & 1048575) * 8;
      in  = seg == 0 ? q  : (seg == 1 ? k  : v);
      out = seg == 0 ? qd : (seg == 1 ? kd : vd);
    } else {
      int c2 = c - 3145728;
      int seg = c2 >> 19; off = (size_t)(c2 & 524287) * 8;
      in  = seg == 0 ? w0 : (seg == 1 ? w1 : (seg == 2 ? w2 : w3));
      out = seg == 0 ? d0 : (seg == 1 ? d1 : (seg == 2 ? d2 : d3));
    }
    float4 a = *(const float4*)(in + off);
    float4 b = *(const float4*)(in + off + 4);
    short8v o;
    o[0] = f2b(a.x); o[1] = f2b(a.y); o[2] = f2b(a.z); o[3] = f2b(a.w);
    o[4] = f2b(b.x); o[5] = f2b(b.y); o[6] = f2b(b.z); o[7] = f2b(b.w);
    *(short8v*)(out + off) = o;
  }
}

// ---------------- async global->LDS, 16B per lane ----------------
__device__ __forceinline__ void gload_lds16(const __hip_bfloat16* g, char* l) {
  __builtin_amdgcn_global_load_lds(
      (const __attribute__((address_space(1))) unsigned int*)g,
      (__attribute__((address_space(3))) unsigned int*)l, 16, 0, 0);
}

// ---------------- GEMM: C[m,n] = sum_k A[m,k]*Bt[n,k] + bias[n] ----------------
// m97 structure: 128x128 tile, 4 waves (64x64 each), BK=32, 16x16x32 bf16 MFMA.
// MODE 0: QK pair (gridDim.z=2 selects A0/A1 set); SWAPPED mfma -> lane holds 4
//         consecutive hd cols; staged in LDS -> 256B-contiguous bf16 stores to [B,H,S,HD].
// MODE 1: V; UNSWAPPED -> lane holds 4 consecutive s rows; staged transposed in LDS ->
//         256B-contiguous bf16 stores to Vt [B,H,HD,S].
// MODE 2: final out fp32 row-major; SWAPPED -> direct f32x4 stores from registers.
template<int MODE>
__global__ __launch_bounds__(256, 2) void gemm_bt2(
    const __hip_bfloat16* __restrict__ A0, const __hip_bfloat16* __restrict__ A1,
    const __hip_bfloat16* __restrict__ B0, const __hip_bfloat16* __restrict__ B1,
    const float* __restrict__ bias0, const float* __restrict__ bias1,
    void* __restrict__ out0, void* __restrict__ out1,
    int M, int N, int K)
{
  __shared__ __align__(16) char smem[MODE == 2 ? 32768 : 34816];
  char* As = smem;            // 128 x 32 bf16 = 16KB
  char* Bs = smem + 16384;    // 16KB
  // epilogue staging (MODE 0/1): bf16 [128][136 padded] = 34816B, aliases As/Bs

  const int z = (MODE == 0) ? blockIdx.z : 0;
  const __hip_bfloat16* A  = z ? A1 : A0;
  const __hip_bfloat16* Bt = z ? B1 : B0;
  const float* bias        = z ? bias1 : bias0;
  void* outp               = z ? out1 : out0;

  const int tid  = threadIdx.x;
  const int lane = tid & 63, wid = tid >> 6;
  const int l16  = lane & 15, g = lane >> 4;
  const int m0 = blockIdx.y * 128, n0 = blockIdx.x * 128;
  const int wm = (wid >> 1) * 64, wn = (wid & 1) * 64;
  const size_t Kz = (size_t)K;

  f32x4 acc[4][4];
#pragma unroll
  for (int i = 0; i < 4; ++i)
#pragma unroll
    for (int j = 0; j < 4; ++j) acc[i][j] = f32x4{0.f, 0.f, 0.f, 0.f};

  const __hip_bfloat16* ga0 = A  + (size_t)(m0 + wid * 32 + (lane >> 2)) * Kz + (lane & 3) * 8;
  const __hip_bfloat16* gb0 = Bt + (size_t)(n0 + wid * 32 + (lane >> 2)) * Kz + (lane & 3) * 8;
  char* lA0 = As + wid * 2048;
  char* lB0 = Bs + wid * 2048;

  const int nk = K >> 5;
  for (int kt = 0; kt < nk; ++kt) {
    __syncthreads();
    gload_lds16(ga0,            lA0);
    gload_lds16(ga0 + 16 * Kz,  lA0 + 1024);
    gload_lds16(gb0,            lB0);
    gload_lds16(gb0 + 16 * Kz,  lB0 + 1024);
    ga0 += 32; gb0 += 32;
    asm volatile("s_waitcnt vmcnt(0)" ::: "memory");
    __syncthreads();
    bf16x8 a[4], b[4];
#pragma unroll
    for (int mf = 0; mf < 4; ++mf)
      a[mf] = *(const bf16x8*)(As + (wm + mf * 16 + l16) * 64 + g * 16);
#pragma unroll
    for (int nf = 0; nf < 4; ++nf)
      b[nf] = *(const bf16x8*)(Bs + (wn + nf * 16 + l16) * 64 + g * 16);
#pragma unroll
    for (int mf = 0; mf < 4; ++mf)
#pragma unroll
      for (int nf = 0; nf < 4; ++nf) {
        if (MODE == 1)
          acc[mf][nf] = __builtin_amdgcn_mfma_f32_16x16x32_bf16(a[mf], b[nf], acc[mf][nf], 0, 0, 0);
        else  // SWAPPED: D row (g*4+r) = n-index, col (l16) = m-index
          acc[mf][nf] = __builtin_amdgcn_mfma_f32_16x16x32_bf16(b[nf], a[mf], acc[mf][nf], 0, 0, 0);
      }
  }

  if (MODE == 2) {
    // swapped: m = m0+wm+mf*16+l16, n = n0+wn+nf*16+g*4+r  -> f32x4 store
    float* C = (float*)outp;
#pragma unroll
    for (int nf = 0; nf < 4; ++nf) {
      f32x4 bv = *(const f32x4*)(bias + n0 + wn + nf * 16 + g * 4);
#pragma unroll
      for (int mf = 0; mf < 4; ++mf) {
        int m = m0 + wm + mf * 16 + l16;
        int n = n0 + wn + nf * 16 + g * 4;
        f32x4 o;
#pragma unroll
        for (int r = 0; r < 4; ++r) o[r] = acc[mf][nf][r] + bv[r];
        *(f32x4*)(C + (size_t)m * N + n) = o;
      }
    }
  } else if (MODE == 0) {
    // swapped: tile-local row s = wm+mf*16+l16, hd = wn+nf*16+g*4+r. Stage [s][hd pad136].
    __syncthreads();
    char* Cs = smem;
#pragma unroll
    for (int nf = 0; nf < 4; ++nf) {
      f32x4 bv = *(const f32x4*)(bias + n0 + wn + nf * 16 + g * 4);
#pragma unroll
      for (int mf = 0; mf < 4; ++mf) {
        int m  = wm + mf * 16 + l16;
        int nc = wn + nf * 16 + g * 4;
        short4v pk;
#pragma unroll
        for (int r = 0; r < 4; ++r) pk[r] = f2b(acc[mf][nf][r] + bv[r]);
        *(short4v*)(Cs + m * 272 + nc * 2) = pk;
      }
    }
    __syncthreads();
    // stream out: 256B contiguous per row of [B,H,S,HD]
    __hip_bfloat16* C = (__hip_bfloat16*)outp;
    const int h = n0 >> 7, bb = m0 >> 10, sbase = m0 & 1023;
    const int c8 = (tid & 15) * 8;
#pragma unroll
    for (int p = 0; p < 8; ++p) {
      int row = p * 16 + (tid >> 4);
      bf16x8 val = *(const bf16x8*)(Cs + row * 272 + c8 * 2);
      *(bf16x8*)(C + (((size_t)bb * 16 + h) * 1024 + sbase + row) * 128 + c8) = val;
    }
  } else { // MODE 1: unswapped: s = wm+mf*16+g*4+r, hd = wn+nf*16+l16. Stage [hd][s pad136].
    __syncthreads();
    char* Cs = smem;
#pragma unroll
    for (int nf = 0; nf < 4; ++nf) {
      float bv = bias[n0 + wn + nf * 16 + l16];
#pragma unroll
      for (int mf = 0; mf < 4; ++mf) {
        int hd = wn + nf * 16 + l16;
        int s0 = wm + mf * 16 + g * 4;
        short4v pk;
#pragma unroll
        for (int r = 0; r < 4; ++r) pk[r] = f2b(acc[mf][nf][r] + bv);
        *(short4v*)(Cs + hd * 272 + s0 * 2) = pk;
      }
    }
    __syncthreads();
    // stream out: 256B contiguous per hd-row of Vt [B,H,HD,S]
    __hip_bfloat16* C = (__hip_bfloat16*)outp;
    const int h = n0 >> 7, bb = m0 >> 10, sbase = m0 & 1023;
    const int c8 = (tid & 15) * 8;
#pragma unroll
    for (int p = 0; p < 8; ++p) {
      int hd = p * 16 + (tid >> 4);
      bf16x8 val = *(const bf16x8*)(Cs + hd * 272 + c8 * 2);
      *(bf16x8*)(C + (((size_t)bb * 16 + h) * 128 + hd) * 1024 + sbase + c8) = val;
    }
  }
}

// ---------------- fused attention, QBLK=32, 8 waves, 32x32 MFMA QK^T ----------------
// 2048 blocks x 512 threads, 2 blocks/CU (66.7KB LDS). bid%8 = XCD (8 heads each).
// Per block: 32 q rows x 1024 keys. QK^T swapped mfma32(K,Q): 4 passes; pass p, wave w
// computes keys [p*256+w*32, +32) x all 32 q rows in ONE 32x32 frag (16 VGPR).
// P = exp(score) stored UNNORMALIZED bf16 in swizzled LDS; row-sums reduced lane-local
// + cross-wave; normalization folded into attn-store (x inv) and final ctx scale.
__global__ __launch_bounds__(512, 4) void attn_kernel(
    const __hip_bfloat16* __restrict__ Qh,   // [64][1024][128]
    const __hip_bfloat16* __restrict__ Kh,   // [64][1024][128]
    const __hip_bfloat16* __restrict__ Vt,   // [64][128][1024]
    float* __restrict__ attn,                // [64][1024][1024]
    __hip_bfloat16* __restrict__ ctx)        // [4][1024][2048]
{
  __shared__ __align__(16) char Plds[32 * 2048];  // bf16 [32 rows][1024 keys], 16B-XOR swizzled
  __shared__ float red[8 * 32];
  __shared__ float invs[32];

  const int tid = threadIdx.x, lane = tid & 63, w = tid >> 6;
  const int l16 = lane & 15, g = lane >> 4;
  const int l31 = lane & 31, kh = lane >> 5;

  const int bid = blockIdx.x;
  const int xcd = bid & 7, j = bid >> 3;          // j in 0..255
  const int bh  = xcd * 8 + (j >> 5);             // 8 heads per XCD
  const int q0  = (j & 31) << 5;                  // 32-row q tile

  const __hip_bfloat16* Qp = Qh + ((size_t)bh * 1024 + q0) * 128;
  const __hip_bfloat16* Kp = Kh + (size_t)bh * 1024 * 128;
  const __hip_bfloat16* Vp = Vt + (size_t)bh * 128 * 1024;
  float* ap = attn + ((size_t)bh * 1024 + q0) * 1024;

  // Q B-frags for 32x32x16: lane holds Q[q0+l31][kh*8 + s*16 ..+8]
  bf16x8 qb[8];
#pragma unroll
  for (int s = 0; s < 8; ++s)
    qb[s] = *(const bf16x8*)(Qp + (size_t)l31 * 128 + s * 16 + kh * 8);

  const float esc = 0.08838834764831845f;   // 1/sqrt(128)
  float rs = 0.f;                           // row-sum partial for qrow l31

  // GEMM1: 4 passes; D[key][qrow]: col=l31 (qrow), row=(reg&3)+8*(reg>>2)+4*kh
#pragma unroll
  for (int pass = 0; pass < 4; ++pass) {
    const int keybase = pass * 256 + w * 32;
    const __hip_bfloat16* kr = Kp + (size_t)(keybase + l31) * 128 + kh * 8;
    bf16x8 kb[8];
#pragma unroll
    for (int s = 0; s < 8; ++s) kb[s] = *(const bf16x8*)(kr + s * 16);
    f32x16 acc;
#pragma unroll
    for (int i = 0; i < 16; ++i) acc[i] = 0.f;
    __builtin_amdgcn_s_setprio(1);
#pragma unroll
    for (int s = 0; s < 8; ++s)
      acc = __builtin_amdgcn_mfma_f32_32x32x16_bf16(kb[s], qb[s], acc, 0, 0, 0);
    __builtin_amdgcn_s_setprio(0);
    // exp, accumulate row-sum, write unnormalized bf16 P to swizzled LDS
#pragma unroll
    for (int grp = 0; grp < 4; ++grp) {
      short4v pk;
#pragma unroll
      for (int jj = 0; jj < 4; ++jj) {
        float e = __expf(acc[grp * 4 + jj] * esc);
        rs += e;
        pk[jj] = f2b(e);
      }
      int key0 = keybase + grp * 8 + kh * 4;
      *(short4v*)(Plds + l31 * 2048 + ((key0 * 2) ^ ((l31 & 7) << 4))) = pk;
    }
  }
  rs += __shfl_xor(rs, 32, 64);             // full 128-key partial for qrow l31
  if (lane < 32) red[w * 32 + l31] = rs;
  __syncthreads();
  if (tid < 32) {
    float t = 0.f;
#pragma unroll
    for (int ww = 0; ww < 8; ++ww) t += red[ww * 32 + tid];
    invs[tid] = 1.0f / t;
  }
  __syncthreads();

  // attn store: wave w streams rows 4w..4w+3 (x inv), NT, 256B contiguous per row chunk
  {
    const int row = 4 * w + g;
    const float invr = invs[row];
    const char* rp = Plds + row * 2048;
    const int sw = (row & 7) << 4;
    float* apr = ap + (size_t)row * 1024;
#pragma unroll
    for (int it = 0; it < 16; ++it) {
      int col = it * 64 + l16 * 4;
      short4v pb = *(const short4v*)(rp + ((col * 2) ^ sw));
      f32x4 val;
#pragma unroll
      for (int r = 0; r < 4; ++r) val[r] = b2f(pb[r]) * invr;
      __builtin_nontemporal_store(val, (f32x4*)(apr + col));
    }
  }

  // PV: ctx[32][128] = P[32][1024] @ V^T (unnormalized); wave w owns hd [16w,16w+16)
  f32x4 acc2[2];
  acc2[0] = f32x4{0.f, 0.f, 0.f, 0.f};
  acc2[1] = f32x4{0.f, 0.f, 0.f, 0.f};
  {
    const char* pr0 = Plds + l16 * 2048;            // qfrag 0 rows 0..15
    const char* pr1 = Plds + (16 + l16) * 2048;     // qfrag 1 rows 16..31
    const int sw = (l16 & 7) << 4;
#pragma unroll 4
    for (int kt = 0; kt < 32; ++kt) {
      int cb = (kt * 64 + g * 16) ^ sw;
      bf16x8 pa0 = *(const bf16x8*)(pr0 + cb);
      bf16x8 pa1 = *(const bf16x8*)(pr1 + cb);
      const __hip_bfloat16* vr = Vp + (size_t)(16 * w + l16) * 1024 + kt * 32 + g * 8;
      bf16x8 vb = *(const bf16x8*)vr;
      __builtin_amdgcn_s_setprio(1);
      acc2[0] = __builtin_amdgcn_mfma_f32_16x16x32_bf16(pa0, vb, acc2[0], 0, 0, 0);
      acc2[1] = __builtin_amdgcn_mfma_f32_16x16x32_bf16(pa1, vb, acc2[1], 0, 0, 0);
      __builtin_amdgcn_s_setprio(0);
    }
  }
  __syncthreads();   // Plds fully consumed

  // ctx staging with deferred normalization: [32][128] bf16 in LDS, then coalesced store
  {
    __hip_bfloat16* cs = (__hip_bfloat16*)Plds;
#pragma unroll
    for (int t = 0; t < 2; ++t) {
      f32x4 iv = *(const f32x4*)(invs + t * 16 + g * 4);
#pragma unroll
      for (int r = 0; r < 4; ++r)
        cs[(t * 16 + g * 4 + r) * 128 + 16 * w + l16] = __float2bfloat16(acc2[t][r] * iv[r]);
    }
    __syncthreads();
    const int row = tid >> 4, c8 = (tid & 15) * 8;   // 32 rows x 128 cols
    bf16x8 val = *(const bf16x8*)(cs + row * 128 + c8);
    const int bb = bh >> 4, h = bh & 15;
    *(bf16x8*)(ctx + ((size_t)(bb * 1024 + q0 + row)) * 2048 + h * 128 + c8) = val;
  }
}

extern "C" void kernel_launch(void* const* d_in, const int* in_sizes, int n_in,
                              void* d_out, int out_size, void* d_ws, size_t ws_size,
                              hipStream_t stream) {
  const float* q    = (const float*)d_in[0];
  const float* k    = (const float*)d_in[1];
  const float* v    = (const float*)d_in[2];
  const float* wq_w = (const float*)d_in[3];
  const float* wq_b = (const float*)d_in[4];
  const float* wk_w = (const float*)d_in[5];
  const float* wk_b = (const float*)d_in[6];
  const float* wv_w = (const float*)d_in[7];
  const float* wv_b = (const float*)d_in[8];
  const float* wo_w = (const float*)d_in[9];
  const float* wo_b = (const float*)d_in[10];

  const size_t BSD = (size_t)4 * 1024 * 2048;  // 8388608
  const size_t DD  = (size_t)2048 * 2048;      // 4194304

  float* out  = (float*)d_out;
  float* attn = out + BSD;                     // 67108864 floats

  __hip_bfloat16* qbf = (__hip_bfloat16*)attn; // scratch in not-yet-written attn region
  __hip_bfloat16* kbf = qbf + BSD;
  __hip_bfloat16* vbf = kbf + BSD;

  __hip_bfloat16* wqb = (__hip_bfloat16*)d_ws;
  __hip_bfloat16* wkb = wqb + DD;
  __hip_bfloat16* wvb = wkb + DD;
  __hip_bfloat16* wob = wvb + DD;
  __hip_bfloat16* Qh  = wob + DD;
  __hip_bfloat16* Kh  = Qh + BSD;
  __hip_bfloat16* Vt  = Kh + BSD;
  __hip_bfloat16* ctx = Vt + BSD;

  cast_all<<<2048, 256, 0, stream>>>(q, k, v, wq_w, wk_w, wv_w, wo_w,
                                     qbf, kbf, vbf, wqb, wkb, wvb, wob);

  dim3 gb(256);
  gemm_bt2<0><<<dim3(16, 32, 2), gb, 0, stream>>>(qbf, kbf, wqb, wkb, wq_b, wk_b,
                                                  Qh, Kh, 4096, 2048, 2048);
  gemm_bt2<1><<<dim3(16, 32), gb, 0, stream>>>(vbf, vbf, wvb, wvb, wv_b, wv_b,
                                               Vt, Vt, 4096, 2048, 2048);

  attn_kernel<<<dim3(2048), dim3(512), 0, stream>>>(Qh, Kh, Vt, attn, ctx);

  gemm_bt2<2><<<dim3(16, 32), gb, 0, stream>>>(ctx, ctx, wob, wob, wo_b, wo_b,
                                               out, out, 4096, 2048, 2048);
}

// Round 7
// 372.338 us; speedup vs baseline: 2.0063x; 1.0195x over previous
//
#include <hip/hip_runtime.h>
#include <hip/hip_bf16.h>

// B=4, S=1024, D=2048, H=16, HD=128. SCALE = sqrt(128).
// d_out = [output fp32 (8388608)] ++ [attn fp32 (67108864)]
// ws layout (bf16): wq,wk,wv,wo [2048*2048 each] | Qh,Kh [B,H,S,HD] | Vt [B,H,HD,S] | ctx [B,S,D]
// attn region of d_out doubles as scratch for bf16 casts of q,k,v (dead before attn kernel writes).

typedef __attribute__((ext_vector_type(4)))  float f32x4;
typedef __attribute__((ext_vector_type(16))) float f32x16;
typedef __attribute__((ext_vector_type(8))) short  bf16x8;   // 8 bf16 in 4 VGPRs
typedef __attribute__((ext_vector_type(4))) short  short4v;
typedef __attribute__((ext_vector_type(8))) short  short8v;

__device__ __forceinline__ short f2b(float f) {
  __hip_bfloat16 h = __float2bfloat16(f);
  return __builtin_bit_cast(short, h);
}
__device__ __forceinline__ float b2f(short s) {
  __hip_bfloat16 h = __builtin_bit_cast(__hip_bfloat16, s);
  return __bfloat162float(h);
}

// ---------------- fused cast fp32->bf16 for all 7 arrays, one launch ----------------
__global__ void cast_all(
    const float* __restrict__ q,  const float* __restrict__ k,  const float* __restrict__ v,
    const float* __restrict__ w0, const float* __restrict__ w1, const float* __restrict__ w2,
    const float* __restrict__ w3,
    __hip_bfloat16* __restrict__ qd, __hip_bfloat16* __restrict__ kd, __hip_bfloat16* __restrict__ vd,
    __hip_bfloat16* __restrict__ d0, __hip_bfloat16* __restrict__ d1, __hip_bfloat16* __restrict__ d2,
    __hip_bfloat16* __restrict__ d3)
{
  const int c0 = blockIdx.x * blockDim.x + threadIdx.x;   // 524288 threads
#pragma unroll
  for (int it = 0; it < 10; ++it) {
    int c = c0 + it * 524288;
    const float* in; __hip_bfloat16* out; size_t off;
    if (c < 3145728) {
      int seg = c >> 20; off = (size_t)(c & 1048575) * 8;
      in  = seg == 0 ? q  : (seg == 1 ? k  : v);
      out = seg == 0 ? qd : (seg == 1 ? kd : vd);
    } else {
      int c2 = c - 3145728;
      int seg = c2 >> 19; off = (size_t)(c2 & 524287) * 8;
      in  = seg == 0 ? w0 : (seg == 1 ? w1 : (seg == 2 ? w2 : w3));
      out = seg == 0 ? d0 : (seg == 1 ? d1 : (seg == 2 ? d2 : d3));
    }
    float4 a = *(const float4*)(in + off);
    float4 b = *(const float4*)(in + off + 4);
    short8v o;
    o[0] = f2b(a.x); o[1] = f2b(a.y); o[2] = f2b(a.z); o[3] = f2b(a.w);
    o[4] = f2b(b.x); o[5] = f2b(b.y); o[6] = f2b(b.z); o[7] = f2b(b.w);
    *(short8v*)(out + off) = o;
  }
}

// ---------------- async global->LDS, 16B per lane ----------------
__device__ __forceinline__ void gload_lds16(const __hip_bfloat16* g, char* l) {
  __builtin_amdgcn_global_load_lds(
      (const __attribute__((address_space(1))) unsigned int*)g,
      (__attribute__((address_space(3))) unsigned int*)l, 16, 0, 0);
}

// ---------------- shared GEMM K-loop (m97 structure, K=N=2048) ----------------
// SWAP=true: mfma(b,a) -> D row = n-frag dim, col = m-frag dim (epilogue-friendly cols)
template<bool SWAP>
__device__ __forceinline__ void gemm_core(
    const __hip_bfloat16* ga0, const __hip_bfloat16* gb0,
    char* As, char* Bs, char* lA0, char* lB0,
    int wm, int wn, int l16, int g, f32x4 (&acc)[4][4])
{
#pragma unroll 1
  for (int kt = 0; kt < 64; ++kt) {
    __syncthreads();
    gload_lds16(ga0,             lA0);
    gload_lds16(ga0 + 16 * 2048, lA0 + 1024);
    gload_lds16(gb0,             lB0);
    gload_lds16(gb0 + 16 * 2048, lB0 + 1024);
    ga0 += 32; gb0 += 32;
    asm volatile("s_waitcnt vmcnt(0)" ::: "memory");
    __syncthreads();
    bf16x8 a[4], b[4];
#pragma unroll
    for (int mf = 0; mf < 4; ++mf)
      a[mf] = *(const bf16x8*)(As + (wm + mf * 16 + l16) * 64 + g * 16);
#pragma unroll
    for (int nf = 0; nf < 4; ++nf)
      b[nf] = *(const bf16x8*)(Bs + (wn + nf * 16 + l16) * 64 + g * 16);
#pragma unroll
    for (int mf = 0; mf < 4; ++mf)
#pragma unroll
      for (int nf = 0; nf < 4; ++nf) {
        if (SWAP)
          acc[mf][nf] = __builtin_amdgcn_mfma_f32_16x16x32_bf16(b[nf], a[mf], acc[mf][nf], 0, 0, 0);
        else
          acc[mf][nf] = __builtin_amdgcn_mfma_f32_16x16x32_bf16(a[mf], b[nf], acc[mf][nf], 0, 0, 0);
      }
  }
}

// ---------------- Q/K/V projections, one launch, z selects ----------------
// z=0: Q (swapped, out [B,H,S,HD]); z=1: K (same); z=2: V (unswapped, out Vt [B,H,HD,S])
__global__ __launch_bounds__(256, 2) void gemm_qkv(
    const __hip_bfloat16* __restrict__ qbf, const __hip_bfloat16* __restrict__ kbf,
    const __hip_bfloat16* __restrict__ vbf,
    const __hip_bfloat16* __restrict__ wqb, const __hip_bfloat16* __restrict__ wkb,
    const __hip_bfloat16* __restrict__ wvb,
    const float* __restrict__ bq, const float* __restrict__ bk, const float* __restrict__ bv,
    __hip_bfloat16* __restrict__ Qh, __hip_bfloat16* __restrict__ Kh,
    __hip_bfloat16* __restrict__ Vt)
{
  __shared__ __align__(16) char smem[34816];
  char* As = smem;
  char* Bs = smem + 16384;

  const int z = blockIdx.z;
  const __hip_bfloat16* A  = z == 0 ? qbf : (z == 1 ? kbf : vbf);
  const __hip_bfloat16* Bt = z == 0 ? wqb : (z == 1 ? wkb : wvb);
  const float* bias        = z == 0 ? bq  : (z == 1 ? bk  : bv);
  __hip_bfloat16* C        = z == 0 ? Qh  : (z == 1 ? Kh  : Vt);

  const int tid  = threadIdx.x;
  const int lane = tid & 63, wid = tid >> 6;
  const int l16  = lane & 15, g = lane >> 4;
  const int m0 = blockIdx.y * 128, n0 = blockIdx.x * 128;
  const int wm = (wid >> 1) * 64, wn = (wid & 1) * 64;

  f32x4 acc[4][4];
#pragma unroll
  for (int i = 0; i < 4; ++i)
#pragma unroll
    for (int j = 0; j < 4; ++j) acc[i][j] = f32x4{0.f, 0.f, 0.f, 0.f};

  const __hip_bfloat16* ga0 = A  + (size_t)(m0 + wid * 32 + (lane >> 2)) * 2048 + (lane & 3) * 8;
  const __hip_bfloat16* gb0 = Bt + (size_t)(n0 + wid * 32 + (lane >> 2)) * 2048 + (lane & 3) * 8;
  char* lA0 = As + wid * 2048;
  char* lB0 = Bs + wid * 2048;

  if (z == 2) gemm_core<false>(ga0, gb0, As, Bs, lA0, lB0, wm, wn, l16, g, acc);
  else        gemm_core<true >(ga0, gb0, As, Bs, lA0, lB0, wm, wn, l16, g, acc);

  const int h = n0 >> 7, bb = m0 >> 10, sbase = m0 & 1023;
  const int c8 = (tid & 15) * 8;
  __syncthreads();
  char* Cs = smem;
  if (z != 2) {
    // swapped: s = wm+mf*16+l16, hd = wn+nf*16+g*4+r. Stage [s][hd pad 136].
#pragma unroll
    for (int nf = 0; nf < 4; ++nf) {
      f32x4 bvv = *(const f32x4*)(bias + n0 + wn + nf * 16 + g * 4);
#pragma unroll
      for (int mf = 0; mf < 4; ++mf) {
        int m  = wm + mf * 16 + l16;
        int nc = wn + nf * 16 + g * 4;
        short4v pk;
#pragma unroll
        for (int r = 0; r < 4; ++r) pk[r] = f2b(acc[mf][nf][r] + bvv[r]);
        *(short4v*)(Cs + m * 272 + nc * 2) = pk;
      }
    }
    __syncthreads();
#pragma unroll
    for (int p = 0; p < 8; ++p) {
      int row = p * 16 + (tid >> 4);
      bf16x8 val = *(const bf16x8*)(Cs + row * 272 + c8 * 2);
      *(bf16x8*)(C + (((size_t)bb * 16 + h) * 1024 + sbase + row) * 128 + c8) = val;
    }
  } else {
    // unswapped: s = wm+mf*16+g*4+r, hd = wn+nf*16+l16. Stage [hd][s pad 136].
#pragma unroll
    for (int nf = 0; nf < 4; ++nf) {
      float bvv = bias[n0 + wn + nf * 16 + l16];
#pragma unroll
      for (int mf = 0; mf < 4; ++mf) {
        int hd = wn + nf * 16 + l16;
        int s0 = wm + mf * 16 + g * 4;
        short4v pk;
#pragma unroll
        for (int r = 0; r < 4; ++r) pk[r] = f2b(acc[mf][nf][r] + bvv);
        *(short4v*)(Cs + hd * 272 + s0 * 2) = pk;
      }
    }
    __syncthreads();
#pragma unroll
    for (int p = 0; p < 8; ++p) {
      int hd = p * 16 + (tid >> 4);
      bf16x8 val = *(const bf16x8*)(Cs + hd * 272 + c8 * 2);
      *(bf16x8*)(C + (((size_t)bb * 16 + h) * 128 + hd) * 1024 + sbase + c8) = val;
    }
  }
}

// ---------------- final output GEMM: out = ctx @ wo^T + b, fp32, swapped ----------------
__global__ __launch_bounds__(256, 2) void gemm_out(
    const __hip_bfloat16* __restrict__ A, const __hip_bfloat16* __restrict__ Bt,
    const float* __restrict__ bias, float* __restrict__ C)
{
  __shared__ __align__(16) char smem[32768];
  char* As = smem;
  char* Bs = smem + 16384;
  const int tid  = threadIdx.x;
  const int lane = tid & 63, wid = tid >> 6;
  const int l16  = lane & 15, g = lane >> 4;
  const int m0 = blockIdx.y * 128, n0 = blockIdx.x * 128;
  const int wm = (wid >> 1) * 64, wn = (wid & 1) * 64;

  f32x4 acc[4][4];
#pragma unroll
  for (int i = 0; i < 4; ++i)
#pragma unroll
    for (int j = 0; j < 4; ++j) acc[i][j] = f32x4{0.f, 0.f, 0.f, 0.f};

  const __hip_bfloat16* ga0 = A  + (size_t)(m0 + wid * 32 + (lane >> 2)) * 2048 + (lane & 3) * 8;
  const __hip_bfloat16* gb0 = Bt + (size_t)(n0 + wid * 32 + (lane >> 2)) * 2048 + (lane & 3) * 8;
  char* lA0 = As + wid * 2048;
  char* lB0 = Bs + wid * 2048;

  gemm_core<true>(ga0, gb0, As, Bs, lA0, lB0, wm, wn, l16, g, acc);

  // swapped: m = m0+wm+mf*16+l16, n = n0+wn+nf*16+g*4+r -> direct f32x4 stores
#pragma unroll
  for (int nf = 0; nf < 4; ++nf) {
    f32x4 bv = *(const f32x4*)(bias + n0 + wn + nf * 16 + g * 4);
#pragma unroll
    for (int mf = 0; mf < 4; ++mf) {
      int m = m0 + wm + mf * 16 + l16;
      int n = n0 + wn + nf * 16 + g * 4;
      f32x4 o;
#pragma unroll
      for (int r = 0; r < 4; ++r) o[r] = acc[mf][nf][r] + bv[r];
      *(f32x4*)(C + (size_t)m * 2048 + n) = o;
    }
  }
}

// ---------------- fused attention, QBLK=32, 8 waves, 32x32 MFMA QK^T ----------------
// 2048 blocks x 512 threads, 2 blocks/CU (66.7KB LDS). bid%8 = XCD (8 heads each).
// Swapped QK^T mfma32(K,Q). P = exp(score) UNNORMALIZED bf16 in swizzled LDS.
// ORDER: QK^T+exp -> PV (no stores in flight => V-load vmcnt waits are clean) ->
// attn NT stores LAST (nothing waits on them) -> ctx. Deferred normalization.
__global__ __launch_bounds__(512, 4) void attn_kernel(
    const __hip_bfloat16* __restrict__ Qh,   // [64][1024][128]
    const __hip_bfloat16* __restrict__ Kh,   // [64][1024][128]
    const __hip_bfloat16* __restrict__ Vt,   // [64][128][1024]
    float* __restrict__ attn,                // [64][1024][1024]
    __hip_bfloat16* __restrict__ ctx)        // [4][1024][2048]
{
  __shared__ __align__(16) char Plds[32 * 2048];  // bf16 [32 rows][1024 keys], 16B-XOR swizzled
  __shared__ float red[8 * 32];
  __shared__ float invs[32];

  const int tid = threadIdx.x, lane = tid & 63, w = tid >> 6;
  const int l16 = lane & 15, g = lane >> 4;
  const int l31 = lane & 31, kh = lane >> 5;

  const int bid = blockIdx.x;
  const int xcd = bid & 7, j = bid >> 3;          // j in 0..255
  const int bh  = xcd * 8 + (j >> 5);             // 8 heads per XCD
  const int q0  = (j & 31) << 5;                  // 32-row q tile

  const __hip_bfloat16* Qp = Qh + ((size_t)bh * 1024 + q0) * 128;
  const __hip_bfloat16* Kp = Kh + (size_t)bh * 1024 * 128;
  const __hip_bfloat16* Vp = Vt + (size_t)bh * 128 * 1024;
  float* ap = attn + ((size_t)bh * 1024 + q0) * 1024;

  // Q B-frags for 32x32x16: lane holds Q[q0+l31][kh*8 + s*16 ..+8]
  bf16x8 qb[8];
#pragma unroll
  for (int s = 0; s < 8; ++s)
    qb[s] = *(const bf16x8*)(Qp + (size_t)l31 * 128 + s * 16 + kh * 8);

  const float esc = 0.08838834764831845f;   // 1/sqrt(128)
  float rs = 0.f;                           // row-sum partial for qrow l31

  // GEMM1: 4 passes; D[key][qrow]: col=l31 (qrow), row=(reg&3)+8*(reg>>2)+4*kh
#pragma unroll
  for (int pass = 0; pass < 4; ++pass) {
    const int keybase = pass * 256 + w * 32;
    const __hip_bfloat16* kr = Kp + (size_t)(keybase + l31) * 128 + kh * 8;
    bf16x8 kb[8];
#pragma unroll
    for (int s = 0; s < 8; ++s) kb[s] = *(const bf16x8*)(kr + s * 16);
    f32x16 acc;
#pragma unroll
    for (int i = 0; i < 16; ++i) acc[i] = 0.f;
    __builtin_amdgcn_s_setprio(1);
#pragma unroll
    for (int s = 0; s < 8; ++s)
      acc = __builtin_amdgcn_mfma_f32_32x32x16_bf16(kb[s], qb[s], acc, 0, 0, 0);
    __builtin_amdgcn_s_setprio(0);
    // exp, accumulate row-sum, write unnormalized bf16 P to swizzled LDS
#pragma unroll
    for (int grp = 0; grp < 4; ++grp) {
      short4v pk;
#pragma unroll
      for (int jj = 0; jj < 4; ++jj) {
        float e = __expf(acc[grp * 4 + jj] * esc);
        rs += e;
        pk[jj] = f2b(e);
      }
      int key0 = keybase + grp * 8 + kh * 4;
      *(short4v*)(Plds + l31 * 2048 + ((key0 * 2) ^ ((l31 & 7) << 4))) = pk;
    }
  }
  rs += __shfl_xor(rs, 32, 64);             // full 128-key partial for qrow l31
  if (lane < 32) red[w * 32 + l31] = rs;
  __syncthreads();                          // P + red complete
  if (tid < 32) {
    float t = 0.f;
#pragma unroll
    for (int ww = 0; ww < 8; ++ww) t += red[ww * 32 + tid];
    invs[tid] = 1.0f / t;                   // other waves proceed to PV without waiting
  }

  // PV FIRST (no stores in flight): ctx[32][128] = P @ V^T (unnormalized);
  // wave w owns hd [16w, 16w+16)
  f32x4 acc2[2];
  acc2[0] = f32x4{0.f, 0.f, 0.f, 0.f};
  acc2[1] = f32x4{0.f, 0.f, 0.f, 0.f};
  {
    const char* pr0 = Plds + l16 * 2048;            // rows 0..15
    const char* pr1 = Plds + (16 + l16) * 2048;     // rows 16..31
    const int sw = (l16 & 7) << 4;
#pragma unroll 4
    for (int kt = 0; kt < 32; ++kt) {
      int cb = (kt * 64 + g * 16) ^ sw;
      bf16x8 pa0 = *(const bf16x8*)(pr0 + cb);
      bf16x8 pa1 = *(const bf16x8*)(pr1 + cb);
      const __hip_bfloat16* vr = Vp + (size_t)(16 * w + l16) * 1024 + kt * 32 + g * 8;
      bf16x8 vb = *(const bf16x8*)vr;
      __builtin_amdgcn_s_setprio(1);
      acc2[0] = __builtin_amdgcn_mfma_f32_16x16x32_bf16(pa0, vb, acc2[0], 0, 0, 0);
      acc2[1] = __builtin_amdgcn_mfma_f32_16x16x32_bf16(pa1, vb, acc2[1], 0, 0, 0);
      __builtin_amdgcn_s_setprio(0);
    }
  }
  __syncthreads();   // invs ready (wave0 wrote before its PV); PV LDS reads done

  // attn store LAST: wave w streams rows 4w..4w+3 (x inv), NT, nothing waits on these
  {
    const int row = 4 * w + g;
    const float invr = invs[row];
    const char* rp = Plds + row * 2048;
    const int sw = (row & 7) << 4;
    float* apr = ap + (size_t)row * 1024;
#pragma unroll
    for (int it = 0; it < 16; ++it) {
      int col = it * 64 + l16 * 4;
      short4v pb = *(const short4v*)(rp + ((col * 2) ^ sw));
      f32x4 val;
#pragma unroll
      for (int r = 0; r < 4; ++r) val[r] = b2f(pb[r]) * invr;
      __builtin_nontemporal_store(val, (f32x4*)(apr + col));
    }
  }
  __syncthreads();   // Plds fully consumed

  // ctx staging with deferred normalization: [32][128] bf16 in LDS, then coalesced store
  {
    __hip_bfloat16* cs = (__hip_bfloat16*)Plds;
#pragma unroll
    for (int t = 0; t < 2; ++t) {
      f32x4 iv = *(const f32x4*)(invs + t * 16 + g * 4);
#pragma unroll
      for (int r = 0; r < 4; ++r)
        cs[(t * 16 + g * 4 + r) * 128 + 16 * w + l16] = __float2bfloat16(acc2[t][r] * iv[r]);
    }
    __syncthreads();
    const int row = tid >> 4, c8 = (tid & 15) * 8;   // 32 rows x 128 cols
    bf16x8 val = *(const bf16x8*)(cs + row * 128 + c8);
    const int bb = bh >> 4, h = bh & 15;
    *(bf16x8*)(ctx + ((size_t)(bb * 1024 + q0 + row)) * 2048 + h * 128 + c8) = val;
  }
}

extern "C" void kernel_launch(void* const* d_in, const int* in_sizes, int n_in,
                              void* d_out, int out_size, void* d_ws, size_t ws_size,
                              hipStream_t stream) {
  const float* q    = (const float*)d_in[0];
  const float* k    = (const float*)d_in[1];
  const float* v    = (const float*)d_in[2];
  const float* wq_w = (const float*)d_in[3];
  const float* wq_b = (const float*)d_in[4];
  const float* wk_w = (const float*)d_in[5];
  const float* wk_b = (const float*)d_in[6];
  const float* wv_w = (const float*)d_in[7];
  const float* wv_b = (const float*)d_in[8];
  const float* wo_w = (const float*)d_in[9];
  const float* wo_b = (const float*)d_in[10];

  const size_t BSD = (size_t)4 * 1024 * 2048;  // 8388608
  const size_t DD  = (size_t)2048 * 2048;      // 4194304

  float* out  = (float*)d_out;
  float* attn = out + BSD;                     // 67108864 floats

  __hip_bfloat16* qbf = (__hip_bfloat16*)attn; // scratch in not-yet-written attn region
  __hip_bfloat16* kbf = qbf + BSD;
  __hip_bfloat16* vbf = kbf + BSD;

  __hip_bfloat16* wqb = (__hip_bfloat16*)d_ws;
  __hip_bfloat16* wkb = wqb + DD;
  __hip_bfloat16* wvb = wkb + DD;
  __hip_bfloat16* wob = wvb + DD;
  __hip_bfloat16* Qh  = wob + DD;
  __hip_bfloat16* Kh  = Qh + BSD;
  __hip_bfloat16* Vt  = Kh + BSD;
  __hip_bfloat16* ctx = Vt + BSD;

  cast_all<<<2048, 256, 0, stream>>>(q, k, v, wq_w, wk_w, wv_w, wo_w,
                                     qbf, kbf, vbf, wqb, wkb, wvb, wob);

  gemm_qkv<<<dim3(16, 32, 3), dim3(256), 0, stream>>>(
      qbf, kbf, vbf, wqb, wkb, wvb, wq_b, wk_b, wv_b, Qh, Kh, Vt);

  attn_kernel<<<dim3(2048), dim3(512), 0, stream>>>(Qh, Kh, Vt, attn, ctx);

  gemm_out<<<dim3(16, 32), dim3(256), 0, stream>>>(ctx, wob, wo_b, out);
}

// Round 8
// 344.023 us; speedup vs baseline: 2.1715x; 1.0823x over previous
//
#include <hip/hip_runtime.h>
#include <hip/hip_bf16.h>

// B=4, S=1024, D=2048, H=16, HD=128. SCALE = sqrt(128).
// d_out = [output fp32 (8388608)] ++ [attn fp32 (67108864)]
// ws layout (bf16): wq,wk,wv,wo [2048*2048 each] | Qh,Kh [B,H,S,HD] | Vt [B,H,HD,S] | ctx [B,S,D]
// attn region of d_out doubles as scratch for bf16 casts of q,k,v (dead before attn kernel writes).

typedef __attribute__((ext_vector_type(4)))  float f32x4;
typedef __attribute__((ext_vector_type(16))) float f32x16;
typedef __attribute__((ext_vector_type(8))) short  bf16x8;   // 8 bf16 in 4 VGPRs
typedef __attribute__((ext_vector_type(4))) short  short4v;
typedef __attribute__((ext_vector_type(8))) short  short8v;

__device__ __forceinline__ short f2b(float f) {
  __hip_bfloat16 h = __float2bfloat16(f);
  return __builtin_bit_cast(short, h);
}
__device__ __forceinline__ float b2f(short s) {
  __hip_bfloat16 h = __builtin_bit_cast(__hip_bfloat16, s);
  return __bfloat162float(h);
}

// ---------------- fused cast fp32->bf16 for all 7 arrays, one launch ----------------
__global__ void cast_all(
    const float* __restrict__ q,  const float* __restrict__ k,  const float* __restrict__ v,
    const float* __restrict__ w0, const float* __restrict__ w1, const float* __restrict__ w2,
    const float* __restrict__ w3,
    __hip_bfloat16* __restrict__ qd, __hip_bfloat16* __restrict__ kd, __hip_bfloat16* __restrict__ vd,
    __hip_bfloat16* __restrict__ d0, __hip_bfloat16* __restrict__ d1, __hip_bfloat16* __restrict__ d2,
    __hip_bfloat16* __restrict__ d3)
{
  const int c0 = blockIdx.x * blockDim.x + threadIdx.x;   // 524288 threads
#pragma unroll
  for (int it = 0; it < 10; ++it) {
    int c = c0 + it * 524288;
    const float* in; __hip_bfloat16* out; size_t off;
    if (c < 3145728) {
      int seg = c >> 20; off = (size_t)(c & 1048575) * 8;
      in  = seg == 0 ? q  : (seg == 1 ? k  : v);
      out = seg == 0 ? qd : (seg == 1 ? kd : vd);
    } else {
      int c2 = c - 3145728;
      int seg = c2 >> 19; off = (size_t)(c2 & 524287) * 8;
      in  = seg == 0 ? w0 : (seg == 1 ? w1 : (seg == 2 ? w2 : w3));
      out = seg == 0 ? d0 : (seg == 1 ? d1 : (seg == 2 ? d2 : d3));
    }
    float4 a = *(const float4*)(in + off);
    float4 b = *(const float4*)(in + off + 4);
    short8v o;
    o[0] = f2b(a.x); o[1] = f2b(a.y); o[2] = f2b(a.z); o[3] = f2b(a.w);
    o[4] = f2b(b.x); o[5] = f2b(b.y); o[6] = f2b(b.z); o[7] = f2b(b.w);
    *(short8v*)(out + off) = o;
  }
}

// ---------------- async global->LDS, 16B per lane ----------------
__device__ __forceinline__ void gload_lds16(const __hip_bfloat16* g, char* l) {
  __builtin_amdgcn_global_load_lds(
      (const __attribute__((address_space(1))) unsigned int*)g,
      (__attribute__((address_space(3))) unsigned int*)l, 16, 0, 0);
}

// ---------------- shared GEMM K-loop, BK=64, K=2048 ----------------
// LDS tiles: As/Bs = 128 rows x 64 bf16 (128 B/row), XOR-swizzled: LDS[row][cb] holds
// global col-byte (cb ^ ((row&7)<<4)). Staged via pre-swizzled global source (the swizzle
// pattern is lane-invariant across the 4 calls since rows step by 8). ds_read_b128 with
// the same XOR is bank-conflict-free. Barrier pairs: 32 (vs 64 at BK=32).
// SWAP=true: mfma(b,a) -> D row = n-frag dim, col = m-frag dim.
template<bool SWAP>
__device__ __forceinline__ void gemm_core64(
    const __hip_bfloat16* ga0, const __hip_bfloat16* gb0,
    char* As, char* Bs, char* lA0, char* lB0,
    int wm, int wn, int l16, int g, f32x4 (&acc)[4][4])
{
  const int sw = (l16 & 7) << 4;
#pragma unroll 1
  for (int kt = 0; kt < 32; ++kt) {
    __syncthreads();
#pragma unroll
    for (int c = 0; c < 4; ++c) {
      gload_lds16(ga0 + c * 16384, lA0 + c * 1024);
      gload_lds16(gb0 + c * 16384, lB0 + c * 1024);
    }
    ga0 += 64; gb0 += 64;
    asm volatile("s_waitcnt vmcnt(0)" ::: "memory");
    __syncthreads();
#pragma unroll
    for (int ks = 0; ks < 2; ++ks) {
      bf16x8 a[4];
#pragma unroll
      for (int mf = 0; mf < 4; ++mf)
        a[mf] = *(const bf16x8*)(As + (wm + mf * 16 + l16) * 128 + ((ks * 64 + g * 16) ^ sw));
#pragma unroll
      for (int nf = 0; nf < 4; ++nf) {
        bf16x8 b = *(const bf16x8*)(Bs + (wn + nf * 16 + l16) * 128 + ((ks * 64 + g * 16) ^ sw));
#pragma unroll
        for (int mf = 0; mf < 4; ++mf) {
          if (SWAP)
            acc[mf][nf] = __builtin_amdgcn_mfma_f32_16x16x32_bf16(b, a[mf], acc[mf][nf], 0, 0, 0);
          else
            acc[mf][nf] = __builtin_amdgcn_mfma_f32_16x16x32_bf16(a[mf], b, acc[mf][nf], 0, 0, 0);
        }
      }
    }
  }
}

// staging source address: row = base + wid*32 + (lane>>3), col elems = ((lane&7)^((lane>>3)&7))*8
__device__ __forceinline__ const __hip_bfloat16* stage_src(
    const __hip_bfloat16* M, int base, int wid, int lane) {
  return M + (size_t)(base + wid * 32 + (lane >> 3)) * 2048
           + (((lane & 7) ^ ((lane >> 3) & 7)) * 8);
}

// ---------------- Q/K/V projections, one launch, z selects ----------------
// z=0: Q (swapped, out [B,H,S,HD]); z=1: K (same); z=2: V (unswapped, out Vt [B,H,HD,S])
__global__ __launch_bounds__(256, 3) void gemm_qkv(
    const __hip_bfloat16* __restrict__ qbf, const __hip_bfloat16* __restrict__ kbf,
    const __hip_bfloat16* __restrict__ vbf,
    const __hip_bfloat16* __restrict__ wqb, const __hip_bfloat16* __restrict__ wkb,
    const __hip_bfloat16* __restrict__ wvb,
    const float* __restrict__ bq, const float* __restrict__ bk, const float* __restrict__ bv,
    __hip_bfloat16* __restrict__ Qh, __hip_bfloat16* __restrict__ Kh,
    __hip_bfloat16* __restrict__ Vt)
{
  __shared__ __align__(16) char smem[32768];
  char* As = smem;
  char* Bs = smem + 16384;

  const int z = blockIdx.z;
  const __hip_bfloat16* A  = z == 0 ? qbf : (z == 1 ? kbf : vbf);
  const __hip_bfloat16* Bt = z == 0 ? wqb : (z == 1 ? wkb : wvb);
  const float* bias        = z == 0 ? bq  : (z == 1 ? bk  : bv);
  __hip_bfloat16* C        = z == 0 ? Qh  : (z == 1 ? Kh  : Vt);

  const int tid  = threadIdx.x;
  const int lane = tid & 63, wid = tid >> 6;
  const int l16  = lane & 15, g = lane >> 4;
  const int m0 = blockIdx.y * 128, n0 = blockIdx.x * 128;
  const int wm = (wid >> 1) * 64, wn = (wid & 1) * 64;

  f32x4 acc[4][4];
#pragma unroll
  for (int i = 0; i < 4; ++i)
#pragma unroll
    for (int j = 0; j < 4; ++j) acc[i][j] = f32x4{0.f, 0.f, 0.f, 0.f};

  const __hip_bfloat16* ga0 = stage_src(A,  m0, wid, lane);
  const __hip_bfloat16* gb0 = stage_src(Bt, n0, wid, lane);
  char* lA0 = As + wid * 4096;
  char* lB0 = Bs + wid * 4096;

  if (z == 2) gemm_core64<false>(ga0, gb0, As, Bs, lA0, lB0, wm, wn, l16, g, acc);
  else        gemm_core64<true >(ga0, gb0, As, Bs, lA0, lB0, wm, wn, l16, g, acc);

  const int hh = n0 >> 7, bb = m0 >> 10, sbase = m0 & 1023;
  const int c8 = (tid & 15) * 8;
  char* Cs = smem;
  if (z != 2) {
    // swapped: s = wm+mf*16+l16, hd = wn+nf*16+g*4+r. Two 64-s-row halves, [64][136 pad].
#pragma unroll
    for (int h = 0; h < 2; ++h) {
      __syncthreads();
      if ((wid >> 1) == h) {
#pragma unroll
        for (int nf = 0; nf < 4; ++nf) {
          f32x4 bvv = *(const f32x4*)(bias + n0 + wn + nf * 16 + g * 4);
#pragma unroll
          for (int mf = 0; mf < 4; ++mf) {
            int sl = mf * 16 + l16;          // 0..63 within half
            int hd = wn + nf * 16 + g * 4;
            short4v pk;
#pragma unroll
            for (int r = 0; r < 4; ++r) pk[r] = f2b(acc[mf][nf][r] + bvv[r]);
            *(short4v*)(Cs + sl * 272 + hd * 2) = pk;
          }
        }
      }
      __syncthreads();
#pragma unroll
      for (int p = 0; p < 4; ++p) {
        int rl = p * 16 + (tid >> 4);
        bf16x8 val = *(const bf16x8*)(Cs + rl * 272 + c8 * 2);
        *(bf16x8*)(C + (((size_t)bb * 16 + hh) * 1024 + sbase + h * 64 + rl) * 128 + c8) = val;
      }
    }
  } else {
    // unswapped: s = wm+mf*16+g*4+r, hd = wn+nf*16+l16. Two 64-hd halves, [64][136 pad].
#pragma unroll
    for (int h = 0; h < 2; ++h) {
      __syncthreads();
      if ((wid & 1) == h) {
#pragma unroll
        for (int nf = 0; nf < 4; ++nf) {
          float bvv = bias[n0 + wn + nf * 16 + l16];
#pragma unroll
          for (int mf = 0; mf < 4; ++mf) {
            int hdl = nf * 16 + l16;         // 0..63 within half
            int s0  = wm + mf * 16 + g * 4;
            short4v pk;
#pragma unroll
            for (int r = 0; r < 4; ++r) pk[r] = f2b(acc[mf][nf][r] + bvv);
            *(short4v*)(Cs + hdl * 272 + s0 * 2) = pk;
          }
        }
      }
      __syncthreads();
#pragma unroll
      for (int p = 0; p < 4; ++p) {
        int rl = p * 16 + (tid >> 4);
        bf16x8 val = *(const bf16x8*)(Cs + rl * 272 + c8 * 2);
        *(bf16x8*)(C + (((size_t)bb * 16 + hh) * 128 + h * 64 + rl) * 1024 + sbase + c8) = val;
      }
    }
  }
}

// ---------------- final output GEMM: out = ctx @ wo^T + b, fp32, swapped ----------------
__global__ __launch_bounds__(256, 3) void gemm_out(
    const __hip_bfloat16* __restrict__ A, const __hip_bfloat16* __restrict__ Bt,
    const float* __restrict__ bias, float* __restrict__ C)
{
  __shared__ __align__(16) char smem[32768];
  char* As = smem;
  char* Bs = smem + 16384;
  const int tid  = threadIdx.x;
  const int lane = tid & 63, wid = tid >> 6;
  const int l16  = lane & 15, g = lane >> 4;
  const int m0 = blockIdx.y * 128, n0 = blockIdx.x * 128;
  const int wm = (wid >> 1) * 64, wn = (wid & 1) * 64;

  f32x4 acc[4][4];
#pragma unroll
  for (int i = 0; i < 4; ++i)
#pragma unroll
    for (int j = 0; j < 4; ++j) acc[i][j] = f32x4{0.f, 0.f, 0.f, 0.f};

  const __hip_bfloat16* ga0 = stage_src(A,  m0, wid, lane);
  const __hip_bfloat16* gb0 = stage_src(Bt, n0, wid, lane);
  char* lA0 = As + wid * 4096;
  char* lB0 = Bs + wid * 4096;

  gemm_core64<true>(ga0, gb0, As, Bs, lA0, lB0, wm, wn, l16, g, acc);

  // swapped: m = m0+wm+mf*16+l16, n = n0+wn+nf*16+g*4+r -> direct f32x4 stores
#pragma unroll
  for (int nf = 0; nf < 4; ++nf) {
    f32x4 bv = *(const f32x4*)(bias + n0 + wn + nf * 16 + g * 4);
#pragma unroll
    for (int mf = 0; mf < 4; ++mf) {
      int m = m0 + wm + mf * 16 + l16;
      int n = n0 + wn + nf * 16 + g * 4;
      f32x4 o;
#pragma unroll
      for (int r = 0; r < 4; ++r) o[r] = acc[mf][nf][r] + bv[r];
      *(f32x4*)(C + (size_t)m * 2048 + n) = o;
    }
  }
}

// ---------------- fused attention, QBLK=32, 8 waves, 32x32 MFMA QK^T ----------------
// 2048 blocks x 512 threads, 2 blocks/CU (66.7KB LDS). bid%8 = XCD (8 heads each).
// Swapped QK^T mfma32(K,Q). P = exp2(score*esc*log2e) UNNORMALIZED bf16 in swizzled LDS.
// Order: QK^T+exp -> PV -> attn NT stores last -> ctx. Deferred normalization.
__global__ __launch_bounds__(512, 4) void attn_kernel(
    const __hip_bfloat16* __restrict__ Qh,   // [64][1024][128]
    const __hip_bfloat16* __restrict__ Kh,   // [64][1024][128]
    const __hip_bfloat16* __restrict__ Vt,   // [64][128][1024]
    float* __restrict__ attn,                // [64][1024][1024]
    __hip_bfloat16* __restrict__ ctx)        // [4][1024][2048]
{
  __shared__ __align__(16) char Plds[32 * 2048];  // bf16 [32 rows][1024 keys], 16B-XOR swizzled
  __shared__ float red[8 * 32];
  __shared__ float invs[32];

  const int tid = threadIdx.x, lane = tid & 63, w = tid >> 6;
  const int l16 = lane & 15, g = lane >> 4;
  const int l31 = lane & 31, kh = lane >> 5;

  const int bid = blockIdx.x;
  const int xcd = bid & 7, j = bid >> 3;          // j in 0..255
  const int bh  = xcd * 8 + (j >> 5);             // 8 heads per XCD
  const int q0  = (j & 31) << 5;                  // 32-row q tile

  const __hip_bfloat16* Qp = Qh + ((size_t)bh * 1024 + q0) * 128;
  const __hip_bfloat16* Kp = Kh + (size_t)bh * 1024 * 128;
  const __hip_bfloat16* Vp = Vt + (size_t)bh * 128 * 1024;
  float* ap = attn + ((size_t)bh * 1024 + q0) * 1024;

  // Q B-frags for 32x32x16: lane holds Q[q0+l31][kh*8 + s*16 ..+8]
  bf16x8 qb[8];
#pragma unroll
  for (int s = 0; s < 8; ++s)
    qb[s] = *(const bf16x8*)(Qp + (size_t)l31 * 128 + s * 16 + kh * 8);

  const float esc2 = 0.12751744f;           // (1/sqrt(128)) * log2(e)
  float rs = 0.f;                           // row-sum partial for qrow l31

  // GEMM1: 4 passes; D[key][qrow]: col=l31 (qrow), row=(reg&3)+8*(reg>>2)+4*kh
#pragma unroll
  for (int pass = 0; pass < 4; ++pass) {
    const int keybase = pass * 256 + w * 32;
    const __hip_bfloat16* kr = Kp + (size_t)(keybase + l31) * 128 + kh * 8;
    bf16x8 kb[8];
#pragma unroll
    for (int s = 0; s < 8; ++s) kb[s] = *(const bf16x8*)(kr + s * 16);
    f32x16 acc;
#pragma unroll
    for (int i = 0; i < 16; ++i) acc[i] = 0.f;
    __builtin_amdgcn_s_setprio(1);
#pragma unroll
    for (int s = 0; s < 8; ++s)
      acc = __builtin_amdgcn_mfma_f32_32x32x16_bf16(kb[s], qb[s], acc, 0, 0, 0);
    __builtin_amdgcn_s_setprio(0);
    // exp2, accumulate row-sum, write unnormalized bf16 P to swizzled LDS
#pragma unroll
    for (int grp = 0; grp < 4; ++grp) {
      short4v pk;
#pragma unroll
      for (int jj = 0; jj < 4; ++jj) {
        float e = exp2f(acc[grp * 4 + jj] * esc2);
        rs += e;
        pk[jj] = f2b(e);
      }
      int key0 = keybase + grp * 8 + kh * 4;
      *(short4v*)(Plds + l31 * 2048 + ((key0 * 2) ^ ((l31 & 7) << 4))) = pk;
    }
  }
  rs += __shfl_xor(rs, 32, 64);             // full 128-key partial for qrow l31
  if (lane < 32) red[w * 32 + l31] = rs;
  __syncthreads();                          // P + red complete
  if (tid < 32) {
    float t = 0.f;
#pragma unroll
    for (int ww = 0; ww < 8; ++ww) t += red[ww * 32 + tid];
    invs[tid] = 1.0f / t;                   // other waves proceed to PV without waiting
  }

  // PV FIRST (no stores in flight): ctx[32][128] = P @ V^T (unnormalized);
  // wave w owns hd [16w, 16w+16)
  f32x4 acc2[2];
  acc2[0] = f32x4{0.f, 0.f, 0.f, 0.f};
  acc2[1] = f32x4{0.f, 0.f, 0.f, 0.f};
  {
    const char* pr0 = Plds + l16 * 2048;            // rows 0..15
    const char* pr1 = Plds + (16 + l16) * 2048;     // rows 16..31
    const int sw = (l16 & 7) << 4;
#pragma unroll 4
    for (int kt = 0; kt < 32; ++kt) {
      int cb = (kt * 64 + g * 16) ^ sw;
      bf16x8 pa0 = *(const bf16x8*)(pr0 + cb);
      bf16x8 pa1 = *(const bf16x8*)(pr1 + cb);
      const __hip_bfloat16* vr = Vp + (size_t)(16 * w + l16) * 1024 + kt * 32 + g * 8;
      bf16x8 vb = *(const bf16x8*)vr;
      __builtin_amdgcn_s_setprio(1);
      acc2[0] = __builtin_amdgcn_mfma_f32_16x16x32_bf16(pa0, vb, acc2[0], 0, 0, 0);
      acc2[1] = __builtin_amdgcn_mfma_f32_16x16x32_bf16(pa1, vb, acc2[1], 0, 0, 0);
      __builtin_amdgcn_s_setprio(0);
    }
  }
  __syncthreads();   // invs ready; PV LDS reads done

  // attn store LAST: wave w streams rows 4w..4w+3 (x inv), NT, nothing waits on these
  {
    const int row = 4 * w + g;
    const float invr = invs[row];
    const char* rp = Plds + row * 2048;
    const int sw = (row & 7) << 4;
    float* apr = ap + (size_t)row * 1024;
#pragma unroll
    for (int it = 0; it < 16; ++it) {
      int col = it * 64 + l16 * 4;
      short4v pb = *(const short4v*)(rp + ((col * 2) ^ sw));
      f32x4 val;
#pragma unroll
      for (int r = 0; r < 4; ++r) val[r] = b2f(pb[r]) * invr;
      __builtin_nontemporal_store(val, (f32x4*)(apr + col));
    }
  }
  __syncthreads();   // Plds fully consumed

  // ctx staging with deferred normalization: [32][128] bf16 in LDS, then coalesced store
  {
    __hip_bfloat16* cs = (__hip_bfloat16*)Plds;
#pragma unroll
    for (int t = 0; t < 2; ++t) {
      f32x4 iv = *(const f32x4*)(invs + t * 16 + g * 4);
#pragma unroll
      for (int r = 0; r < 4; ++r)
        cs[(t * 16 + g * 4 + r) * 128 + 16 * w + l16] = __float2bfloat16(acc2[t][r] * iv[r]);
    }
    __syncthreads();
    const int row = tid >> 4, c8 = (tid & 15) * 8;   // 32 rows x 128 cols
    bf16x8 val = *(const bf16x8*)(cs + row * 128 + c8);
    const int bb = bh >> 4, h = bh & 15;
    *(bf16x8*)(ctx + ((size_t)(bb * 1024 + q0 + row)) * 2048 + h * 128 + c8) = val;
  }
}

extern "C" void kernel_launch(void* const* d_in, const int* in_sizes, int n_in,
                              void* d_out, int out_size, void* d_ws, size_t ws_size,
                              hipStream_t stream) {
  const float* q    = (const float*)d_in[0];
  const float* k    = (const float*)d_in[1];
  const float* v    = (const float*)d_in[2];
  const float* wq_w = (const float*)d_in[3];
  const float* wq_b = (const float*)d_in[4];
  const float* wk_w = (const float*)d_in[5];
  const float* wk_b = (const float*)d_in[6];
  const float* wv_w = (const float*)d_in[7];
  const float* wv_b = (const float*)d_in[8];
  const float* wo_w = (const float*)d_in[9];
  const float* wo_b = (const float*)d_in[10];

  const size_t BSD = (size_t)4 * 1024 * 2048;  // 8388608
  const size_t DD  = (size_t)2048 * 2048;      // 4194304

  float* out  = (float*)d_out;
  float* attn = out + BSD;                     // 67108864 floats

  __hip_bfloat16* qbf = (__hip_bfloat16*)attn; // scratch in not-yet-written attn region
  __hip_bfloat16* kbf = qbf + BSD;
  __hip_bfloat16* vbf = kbf + BSD;

  __hip_bfloat16* wqb = (__hip_bfloat16*)d_ws;
  __hip_bfloat16* wkb = wqb + DD;
  __hip_bfloat16* wvb = wkb + DD;
  __hip_bfloat16* wob = wvb + DD;
  __hip_bfloat16* Qh  = wob + DD;
  __hip_bfloat16* Kh  = Qh + BSD;
  __hip_bfloat16* Vt  = Kh + BSD;
  __hip_bfloat16* ctx = Vt + BSD;

  cast_all<<<2048, 256, 0, stream>>>(q, k, v, wq_w, wk_w, wv_w, wo_w,
                                     qbf, kbf, vbf, wqb, wkb, wvb, wob);

  gemm_qkv<<<dim3(16, 32, 3), dim3(256), 0, stream>>>(
      qbf, kbf, vbf, wqb, wkb, wvb, wq_b, wk_b, wv_b, Qh, Kh, Vt);

  attn_kernel<<<dim3(2048), dim3(512), 0, stream>>>(Qh, Kh, Vt, attn, ctx);

  gemm_out<<<dim3(16, 32), dim3(256), 0, stream>>>(ctx, wob, wo_b, out);
}

// Round 10
// 332.930 us; speedup vs baseline: 2.2438x; 1.0333x over previous
//
#include <hip/hip_runtime.h>
#include <hip/hip_bf16.h>

// B=4, S=1024, D=2048, H=16, HD=128. SCALE = sqrt(128).
// d_out = [output fp32 (8388608)] ++ [attn fp32 (67108864)]
// ws layout (bf16): wq,wk,wv,wo [2048*2048 each] | Qh,Kh [B,H,S,HD] | Vt [B,H,HD,S] | ctx [B,S,D]
// attn region of d_out doubles as scratch for bf16 casts of q,k,v (dead before attn kernel writes).

typedef __attribute__((ext_vector_type(4)))  float f32x4;
typedef __attribute__((ext_vector_type(16))) float f32x16;
typedef __attribute__((ext_vector_type(8))) short  bf16x8;   // 8 bf16 in 4 VGPRs
typedef __attribute__((ext_vector_type(4))) short  short4v;
typedef __attribute__((ext_vector_type(8))) short  short8v;

__device__ __forceinline__ short f2b(float f) {
  __hip_bfloat16 h = __float2bfloat16(f);
  return __builtin_bit_cast(short, h);
}
__device__ __forceinline__ float b2f(short s) {
  __hip_bfloat16 h = __builtin_bit_cast(__hip_bfloat16, s);
  return __bfloat162float(h);
}

// ---------------- fused cast fp32->bf16 for all 7 arrays, one launch ----------------
__global__ void cast_all(
    const float* __restrict__ q,  const float* __restrict__ k,  const float* __restrict__ v,
    const float* __restrict__ w0, const float* __restrict__ w1, const float* __restrict__ w2,
    const float* __restrict__ w3,
    __hip_bfloat16* __restrict__ qd, __hip_bfloat16* __restrict__ kd, __hip_bfloat16* __restrict__ vd,
    __hip_bfloat16* __restrict__ d0, __hip_bfloat16* __restrict__ d1, __hip_bfloat16* __restrict__ d2,
    __hip_bfloat16* __restrict__ d3)
{
  const int c0 = blockIdx.x * blockDim.x + threadIdx.x;   // 524288 threads
#pragma unroll
  for (int it = 0; it < 10; ++it) {
    int c = c0 + it * 524288;
    const float* in; __hip_bfloat16* out; size_t off;
    if (c < 3145728) {
      int seg = c >> 20; off = (size_t)(c & 1048575) * 8;
      in  = seg == 0 ? q  : (seg == 1 ? k  : v);
      out = seg == 0 ? qd : (seg == 1 ? kd : vd);
    } else {
      int c2 = c - 3145728;
      int seg = c2 >> 19; off = (size_t)(c2 & 524287) * 8;
      in  = seg == 0 ? w0 : (seg == 1 ? w1 : (seg == 2 ? w2 : w3));
      out = seg == 0 ? d0 : (seg == 1 ? d1 : (seg == 2 ? d2 : d3));
    }
    float4 a = *(const float4*)(in + off);
    float4 b = *(const float4*)(in + off + 4);
    short8v o;
    o[0] = f2b(a.x); o[1] = f2b(a.y); o[2] = f2b(a.z); o[3] = f2b(a.w);
    o[4] = f2b(b.x); o[5] = f2b(b.y); o[6] = f2b(b.z); o[7] = f2b(b.w);
    *(short8v*)(out + off) = o;
  }
}

// ---------------- async global->LDS, 16B per lane ----------------
__device__ __forceinline__ void gload_lds16(const __hip_bfloat16* g, char* l) {
  __builtin_amdgcn_global_load_lds(
      (const __attribute__((address_space(1))) unsigned int*)g,
      (__attribute__((address_space(3))) unsigned int*)l, 16, 0, 0);
}

// ---------------- shared GEMM K-loop, BK=64, K=2048 ----------------
// LDS tiles: As/Bs = 128 rows x 64 bf16 (128 B/row), XOR-swizzled (pre-swizzled global
// source + same XOR on ds_read_b128). 32 barrier pairs.
// SWAP=true: mfma(b,a) -> D row = n-frag dim, col = m-frag dim.
template<bool SWAP>
__device__ __forceinline__ void gemm_core64(
    const __hip_bfloat16* ga0, const __hip_bfloat16* gb0,
    char* As, char* Bs, char* lA0, char* lB0,
    int wm, int wn, int l16, int g, f32x4 (&acc)[4][4])
{
  const int sw = (l16 & 7) << 4;
#pragma unroll 1
  for (int kt = 0; kt < 32; ++kt) {
    __syncthreads();
#pragma unroll
    for (int c = 0; c < 4; ++c) {
      gload_lds16(ga0 + c * 16384, lA0 + c * 1024);
      gload_lds16(gb0 + c * 16384, lB0 + c * 1024);
    }
    ga0 += 64; gb0 += 64;
    asm volatile("s_waitcnt vmcnt(0)" ::: "memory");
    __syncthreads();
#pragma unroll
    for (int ks = 0; ks < 2; ++ks) {
      bf16x8 a[4];
#pragma unroll
      for (int mf = 0; mf < 4; ++mf)
        a[mf] = *(const bf16x8*)(As + (wm + mf * 16 + l16) * 128 + ((ks * 64 + g * 16) ^ sw));
#pragma unroll
      for (int nf = 0; nf < 4; ++nf) {
        bf16x8 b = *(const bf16x8*)(Bs + (wn + nf * 16 + l16) * 128 + ((ks * 64 + g * 16) ^ sw));
#pragma unroll
        for (int mf = 0; mf < 4; ++mf) {
          if (SWAP)
            acc[mf][nf] = __builtin_amdgcn_mfma_f32_16x16x32_bf16(b, a[mf], acc[mf][nf], 0, 0, 0);
          else
            acc[mf][nf] = __builtin_amdgcn_mfma_f32_16x16x32_bf16(a[mf], b, acc[mf][nf], 0, 0, 0);
        }
      }
    }
  }
}

// staging source address: row = base + wid*32 + (lane>>3), col elems = ((lane&7)^((lane>>3)&7))*8
__device__ __forceinline__ const __hip_bfloat16* stage_src(
    const __hip_bfloat16* M, int base, int wid, int lane) {
  return M + (size_t)(base + wid * 32 + (lane >> 3)) * 2048
           + (((lane & 7) ^ ((lane >> 3) & 7)) * 8);
}

// ---------------- Q/K/V projections, one launch, z selects ----------------
// z=0: Q (swapped, out [B,H,S,HD]); z=1: K (same); z=2: V (unswapped, out Vt [B,H,HD,S])
__global__ __launch_bounds__(256, 3) void gemm_qkv(
    const __hip_bfloat16* __restrict__ qbf, const __hip_bfloat16* __restrict__ kbf,
    const __hip_bfloat16* __restrict__ vbf,
    const __hip_bfloat16* __restrict__ wqb, const __hip_bfloat16* __restrict__ wkb,
    const __hip_bfloat16* __restrict__ wvb,
    const float* __restrict__ bq, const float* __restrict__ bk, const float* __restrict__ bv,
    __hip_bfloat16* __restrict__ Qh, __hip_bfloat16* __restrict__ Kh,
    __hip_bfloat16* __restrict__ Vt)
{
  __shared__ __align__(16) char smem[32768];
  char* As = smem;
  char* Bs = smem + 16384;

  const int z = blockIdx.z;
  const __hip_bfloat16* A  = z == 0 ? qbf : (z == 1 ? kbf : vbf);
  const __hip_bfloat16* Bt = z == 0 ? wqb : (z == 1 ? wkb : wvb);
  const float* bias        = z == 0 ? bq  : (z == 1 ? bk  : bv);
  __hip_bfloat16* C        = z == 0 ? Qh  : (z == 1 ? Kh  : Vt);

  const int tid  = threadIdx.x;
  const int lane = tid & 63, wid = tid >> 6;
  const int l16  = lane & 15, g = lane >> 4;
  const int m0 = blockIdx.y * 128, n0 = blockIdx.x * 128;
  const int wm = (wid >> 1) * 64, wn = (wid & 1) * 64;

  f32x4 acc[4][4];
#pragma unroll
  for (int i = 0; i < 4; ++i)
#pragma unroll
    for (int j = 0; j < 4; ++j) acc[i][j] = f32x4{0.f, 0.f, 0.f, 0.f};

  const __hip_bfloat16* ga0 = stage_src(A,  m0, wid, lane);
  const __hip_bfloat16* gb0 = stage_src(Bt, n0, wid, lane);
  char* lA0 = As + wid * 4096;
  char* lB0 = Bs + wid * 4096;

  if (z == 2) gemm_core64<false>(ga0, gb0, As, Bs, lA0, lB0, wm, wn, l16, g, acc);
  else        gemm_core64<true >(ga0, gb0, As, Bs, lA0, lB0, wm, wn, l16, g, acc);

  const int hh = n0 >> 7, bb = m0 >> 10, sbase = m0 & 1023;
  const int c8 = (tid & 15) * 8;
  char* Cs = smem;
  if (z != 2) {
    // swapped: s = wm+mf*16+l16, hd = wn+nf*16+g*4+r. Two 64-s-row halves, [64][136 pad].
#pragma unroll
    for (int h = 0; h < 2; ++h) {
      __syncthreads();
      if ((wid >> 1) == h) {
#pragma unroll
        for (int nf = 0; nf < 4; ++nf) {
          f32x4 bvv = *(const f32x4*)(bias + n0 + wn + nf * 16 + g * 4);
#pragma unroll
          for (int mf = 0; mf < 4; ++mf) {
            int sl = mf * 16 + l16;          // 0..63 within half
            int hd = wn + nf * 16 + g * 4;
            short4v pk;
#pragma unroll
            for (int r = 0; r < 4; ++r) pk[r] = f2b(acc[mf][nf][r] + bvv[r]);
            *(short4v*)(Cs + sl * 272 + hd * 2) = pk;
          }
        }
      }
      __syncthreads();
#pragma unroll
      for (int p = 0; p < 4; ++p) {
        int rl = p * 16 + (tid >> 4);
        bf16x8 val = *(const bf16x8*)(Cs + rl * 272 + c8 * 2);
        *(bf16x8*)(C + (((size_t)bb * 16 + hh) * 1024 + sbase + h * 64 + rl) * 128 + c8) = val;
      }
    }
  } else {
    // unswapped: s = wm+mf*16+g*4+r, hd = wn+nf*16+l16. Two 64-hd halves, [64][136 pad].
#pragma unroll
    for (int h = 0; h < 2; ++h) {
      __syncthreads();
      if ((wid & 1) == h) {
#pragma unroll
        for (int nf = 0; nf < 4; ++nf) {
          float bvv = bias[n0 + wn + nf * 16 + l16];
#pragma unroll
          for (int mf = 0; mf < 4; ++mf) {
            int hdl = nf * 16 + l16;         // 0..63 within half
            int s0  = wm + mf * 16 + g * 4;
            short4v pk;
#pragma unroll
            for (int r = 0; r < 4; ++r) pk[r] = f2b(acc[mf][nf][r] + bvv);
            *(short4v*)(Cs + hdl * 272 + s0 * 2) = pk;
          }
        }
      }
      __syncthreads();
#pragma unroll
      for (int p = 0; p < 4; ++p) {
        int rl = p * 16 + (tid >> 4);
        bf16x8 val = *(const bf16x8*)(Cs + rl * 272 + c8 * 2);
        *(bf16x8*)(C + (((size_t)bb * 16 + hh) * 128 + h * 64 + rl) * 1024 + sbase + c8) = val;
      }
    }
  }
}

// ---------------- final output GEMM: out = ctx @ wo^T + b, fp32, swapped ----------------
__global__ __launch_bounds__(256, 3) void gemm_out(
    const __hip_bfloat16* __restrict__ A, const __hip_bfloat16* __restrict__ Bt,
    const float* __restrict__ bias, float* __restrict__ C)
{
  __shared__ __align__(16) char smem[32768];
  char* As = smem;
  char* Bs = smem + 16384;
  const int tid  = threadIdx.x;
  const int lane = tid & 63, wid = tid >> 6;
  const int l16  = lane & 15, g = lane >> 4;
  const int m0 = blockIdx.y * 128, n0 = blockIdx.x * 128;
  const int wm = (wid >> 1) * 64, wn = (wid & 1) * 64;

  f32x4 acc[4][4];
#pragma unroll
  for (int i = 0; i < 4; ++i)
#pragma unroll
    for (int j = 0; j < 4; ++j) acc[i][j] = f32x4{0.f, 0.f, 0.f, 0.f};

  const __hip_bfloat16* ga0 = stage_src(A,  m0, wid, lane);
  const __hip_bfloat16* gb0 = stage_src(Bt, n0, wid, lane);
  char* lA0 = As + wid * 4096;
  char* lB0 = Bs + wid * 4096;

  gemm_core64<true>(ga0, gb0, As, Bs, lA0, lB0, wm, wn, l16, g, acc);

  // swapped: m = m0+wm+mf*16+l16, n = n0+wn+nf*16+g*4+r -> direct f32x4 stores
#pragma unroll
  for (int nf = 0; nf < 4; ++nf) {
    f32x4 bv = *(const f32x4*)(bias + n0 + wn + nf * 16 + g * 4);
#pragma unroll
    for (int mf = 0; mf < 4; ++mf) {
      int m = m0 + wm + mf * 16 + l16;
      int n = n0 + wn + nf * 16 + g * 4;
      f32x4 o;
#pragma unroll
      for (int r = 0; r < 4; ++r) o[r] = acc[mf][nf][r] + bv[r];
      *(f32x4*)(C + (size_t)m * 2048 + n) = o;
    }
  }
}

// ---------------- fused attention, QBLK=32, 8 waves, wave-specialized tail ----------------
// 2048 blocks x 512 threads, 2 blocks/CU (~73KB LDS). bid%8 = XCD (8 heads each).
// QK^T: swapped mfma32(K,Q), all 8 waves, P=exp2 unnormalized bf16 -> swizzled LDS.
// After rowsum: WAVES 0-3 run PV (each owns 32 hd cols, 4 MFMA/kt) while WAVES 4-7
// stream the 32 attn rows as NT stores (x inv) CONCURRENTLY — store pipe || MFMA pipe.
// ctx staged in a separate 8KB LDS buffer (deferred normalization); ALL 512 threads store.
__global__ __launch_bounds__(512, 4) void attn_kernel(
    const __hip_bfloat16* __restrict__ Qh,   // [64][1024][128]
    const __hip_bfloat16* __restrict__ Kh,   // [64][1024][128]
    const __hip_bfloat16* __restrict__ Vt,   // [64][128][1024]
    float* __restrict__ attn,                // [64][1024][1024]
    __hip_bfloat16* __restrict__ ctx)        // [4][1024][2048]
{
  __shared__ __align__(16) char Plds[32 * 2048];       // bf16 [32][1024], 16B-XOR swizzled
  __shared__ __align__(16) __hip_bfloat16 cs[32 * 128]; // ctx staging, 8KB
  __shared__ float red[8 * 32];
  __shared__ float invs[32];

  const int tid = threadIdx.x, lane = tid & 63, w = tid >> 6;
  const int l16 = lane & 15, g = lane >> 4;
  const int l31 = lane & 31, kh = lane >> 5;

  const int bid = blockIdx.x;
  const int xcd = bid & 7, j = bid >> 3;          // j in 0..255
  const int bh  = xcd * 8 + (j >> 5);             // 8 heads per XCD
  const int q0  = (j & 31) << 5;                  // 32-row q tile

  const __hip_bfloat16* Qp = Qh + ((size_t)bh * 1024 + q0) * 128;
  const __hip_bfloat16* Kp = Kh + (size_t)bh * 1024 * 128;
  const __hip_bfloat16* Vp = Vt + (size_t)bh * 128 * 1024;
  float* ap = attn + ((size_t)bh * 1024 + q0) * 1024;

  // Q B-frags for 32x32x16: lane holds Q[q0+l31][kh*8 + s*16 ..+8]
  bf16x8 qb[8];
#pragma unroll
  for (int s = 0; s < 8; ++s)
    qb[s] = *(const bf16x8*)(Qp + (size_t)l31 * 128 + s * 16 + kh * 8);

  const float esc2 = 0.12751744f;           // (1/sqrt(128)) * log2(e)
  float rs = 0.f;                           // row-sum partial for qrow l31

  // GEMM1: 4 passes; D[key][qrow]: col=l31 (qrow), row=(reg&3)+8*(reg>>2)+4*kh
#pragma unroll
  for (int pass = 0; pass < 4; ++pass) {
    const int keybase = pass * 256 + w * 32;
    const __hip_bfloat16* kr = Kp + (size_t)(keybase + l31) * 128 + kh * 8;
    bf16x8 kb[8];
#pragma unroll
    for (int s = 0; s < 8; ++s) kb[s] = *(const bf16x8*)(kr + s * 16);
    f32x16 acc;
#pragma unroll
    for (int i = 0; i < 16; ++i) acc[i] = 0.f;
    __builtin_amdgcn_s_setprio(1);
#pragma unroll
    for (int s = 0; s < 8; ++s)
      acc = __builtin_amdgcn_mfma_f32_32x32x16_bf16(kb[s], qb[s], acc, 0, 0, 0);
    __builtin_amdgcn_s_setprio(0);
    // exp2, accumulate row-sum, write unnormalized bf16 P to swizzled LDS
#pragma unroll
    for (int grp = 0; grp < 4; ++grp) {
      short4v pk;
#pragma unroll
      for (int jj = 0; jj < 4; ++jj) {
        float e = exp2f(acc[grp * 4 + jj] * esc2);
        rs += e;
        pk[jj] = f2b(e);
      }
      int key0 = keybase + grp * 8 + kh * 4;
      *(short4v*)(Plds + l31 * 2048 + ((key0 * 2) ^ ((l31 & 7) << 4))) = pk;
    }
  }
  rs += __shfl_xor(rs, 32, 64);             // full 128-key partial for qrow l31
  if (lane < 32) red[w * 32 + l31] = rs;
  __syncthreads();                          // P + red complete
  if (tid < 32) {
    float t = 0.f;
#pragma unroll
    for (int ww = 0; ww < 8; ++ww) t += red[ww * 32 + tid];
    invs[tid] = 1.0f / t;
  }
  __syncthreads();                          // invs visible to all waves

  // ---- wave-specialized concurrent tail (no barriers inside either branch) ----
  if (w < 4) {
    // PV: wave w owns hd [32w, 32w+32): acc2[t][f2] -> ctx[q=t*16+g*4+r][hd=32w+f2*16+l16]
    f32x4 acc2[2][2];
#pragma unroll
    for (int t = 0; t < 2; ++t)
#pragma unroll
      for (int f2 = 0; f2 < 2; ++f2) acc2[t][f2] = f32x4{0.f, 0.f, 0.f, 0.f};
    const char* pr0 = Plds + l16 * 2048;            // P rows 0..15
    const char* pr1 = Plds + (16 + l16) * 2048;     // P rows 16..31 (same swizzle: l16&7)
    const int sw = (l16 & 7) << 4;
    const __hip_bfloat16* vr0 = Vp + (size_t)(32 * w + l16) * 1024;
    const __hip_bfloat16* vr1 = Vp + (size_t)(32 * w + 16 + l16) * 1024;
#pragma unroll 4
    for (int kt = 0; kt < 32; ++kt) {
      int cb = (kt * 64 + g * 16) ^ sw;
      bf16x8 pa0 = *(const bf16x8*)(pr0 + cb);
      bf16x8 pa1 = *(const bf16x8*)(pr1 + cb);
      bf16x8 vb0 = *(const bf16x8*)(vr0 + kt * 32 + g * 8);
      bf16x8 vb1 = *(const bf16x8*)(vr1 + kt * 32 + g * 8);
      __builtin_amdgcn_s_setprio(1);
      acc2[0][0] = __builtin_amdgcn_mfma_f32_16x16x32_bf16(pa0, vb0, acc2[0][0], 0, 0, 0);
      acc2[1][0] = __builtin_amdgcn_mfma_f32_16x16x32_bf16(pa1, vb0, acc2[1][0], 0, 0, 0);
      acc2[0][1] = __builtin_amdgcn_mfma_f32_16x16x32_bf16(pa0, vb1, acc2[0][1], 0, 0, 0);
      acc2[1][1] = __builtin_amdgcn_mfma_f32_16x16x32_bf16(pa1, vb1, acc2[1][1], 0, 0, 0);
      __builtin_amdgcn_s_setprio(0);
    }
    // ctx staging with deferred normalization
#pragma unroll
    for (int t = 0; t < 2; ++t) {
      f32x4 iv = *(const f32x4*)(invs + t * 16 + g * 4);
#pragma unroll
      for (int f2 = 0; f2 < 2; ++f2)
#pragma unroll
        for (int r = 0; r < 4; ++r)
          cs[(t * 16 + g * 4 + r) * 128 + 32 * w + f2 * 16 + l16] =
              __float2bfloat16(acc2[t][f2][r] * iv[r]);
    }
  } else {
    // attn store: wave w-4 streams rows (w-4)*8 + rr*4 + g (x inv), NT
#pragma unroll
    for (int rr = 0; rr < 2; ++rr) {
      const int row = (w - 4) * 8 + rr * 4 + g;
      const float invr = invs[row];
      const char* rp = Plds + row * 2048;
      const int swr = (row & 7) << 4;
      float* apr = ap + (size_t)row * 1024;
#pragma unroll
      for (int it = 0; it < 16; ++it) {
        int col = it * 64 + l16 * 4;
        short4v pb = *(const short4v*)(rp + ((col * 2) ^ swr));
        f32x4 val;
#pragma unroll
        for (int r = 0; r < 4; ++r) val[r] = b2f(pb[r]) * invr;
        __builtin_nontemporal_store(val, (f32x4*)(apr + col));
      }
    }
  }
  __syncthreads();   // cs complete; attn stores issued

  // ctx global store: ALL 512 threads, 16B each -> 32 rows x 128 cols, 256B per row
  {
    const int row = tid >> 4, c8 = (tid & 15) * 8;
    bf16x8 val = *(const bf16x8*)(cs + row * 128 + c8);
    const int bb = bh >> 4, h = bh & 15;
    *(bf16x8*)(ctx + ((size_t)(bb * 1024 + q0 + row)) * 2048 + h * 128 + c8) = val;
  }
}

extern "C" void kernel_launch(void* const* d_in, const int* in_sizes, int n_in,
                              void* d_out, int out_size, void* d_ws, size_t ws_size,
                              hipStream_t stream) {
  const float* q    = (const float*)d_in[0];
  const float* k    = (const float*)d_in[1];
  const float* v    = (const float*)d_in[2];
  const float* wq_w = (const float*)d_in[3];
  const float* wq_b = (const float*)d_in[4];
  const float* wk_w = (const float*)d_in[5];
  const float* wk_b = (const float*)d_in[6];
  const float* wv_w = (const float*)d_in[7];
  const float* wv_b = (const float*)d_in[8];
  const float* wo_w = (const float*)d_in[9];
  const float* wo_b = (const float*)d_in[10];

  const size_t BSD = (size_t)4 * 1024 * 2048;  // 8388608
  const size_t DD  = (size_t)2048 * 2048;      // 4194304

  float* out  = (float*)d_out;
  float* attn = out + BSD;                     // 67108864 floats

  __hip_bfloat16* qbf = (__hip_bfloat16*)attn; // scratch in not-yet-written attn region
  __hip_bfloat16* kbf = qbf + BSD;
  __hip_bfloat16* vbf = kbf + BSD;

  __hip_bfloat16* wqb = (__hip_bfloat16*)d_ws;
  __hip_bfloat16* wkb = wqb + DD;
  __hip_bfloat16* wvb = wkb + DD;
  __hip_bfloat16* wob = wvb + DD;
  __hip_bfloat16* Qh  = wob + DD;
  __hip_bfloat16* Kh  = Qh + BSD;
  __hip_bfloat16* Vt  = Kh + BSD;
  __hip_bfloat16* ctx = Vt + BSD;

  cast_all<<<2048, 256, 0, stream>>>(q, k, v, wq_w, wk_w, wv_w, wo_w,
                                     qbf, kbf, vbf, wqb, wkb, wvb, wob);

  gemm_qkv<<<dim3(16, 32, 3), dim3(256), 0, stream>>>(
      qbf, kbf, vbf, wqb, wkb, wvb, wq_b, wk_b, wv_b, Qh, Kh, Vt);

  attn_kernel<<<dim3(2048), dim3(512), 0, stream>>>(Qh, Kh, Vt, attn, ctx);

  gemm_out<<<dim3(16, 32), dim3(256), 0, stream>>>(ctx, wob, wo_b, out);
}